// Round 9
// baseline (10702.294 us; speedup 1.0000x reference)
//
#include <hip/hip_runtime.h>
#include <hip/hip_bf16.h>

#define TT 512
#define BB 128
#define HH 512
#define NGROUP 8          // batch groups, 16 rows each
#define NSLICE 8          // col-slice blocks per group (4 waves x 16 cols each)
#define ALPHA 0.1f
#define NOISE_S 0.02f

typedef __attribute__((ext_vector_type(8))) short short8;
typedef __attribute__((ext_vector_type(8))) _Float16 half8;
typedef __attribute__((ext_vector_type(4))) float f32x4;
typedef __attribute__((ext_vector_type(4))) unsigned u32x4;

// ---- workspace layout (bytes) ----
#define WPACK_CH 132096                       // 16B chunks of packed weights
#define PUB1_B (WPACK_CH * 16)                // tanh1 pub: [NGROUP][8192] u32 words
#define PUB2_B (PUB1_B + NGROUP * 32768)      // tanh2 pub: [NGROUP][8192] u32 words
// word = (step_tag << 16) | fp16_bits ; word idx = kt*512 + srow*8 + j

__device__ __forceinline__ unsigned short f2h(float f) {
  return __builtin_bit_cast(unsigned short, (_Float16)f);  // RNE
}

__device__ __forceinline__ float fast_tanh(float x) {
  float e = __builtin_amdgcn_exp2f(x * 2.8853900817779268f);
  return 1.0f - 2.0f * __builtin_amdgcn_rcpf(e + 1.0f);
}

__device__ __forceinline__ f32x4 mfma16(short8 a, short8 b, f32x4 c) {
  return __builtin_amdgcn_mfma_f32_16x16x32_f16(
      __builtin_bit_cast(half8, a), __builtin_bit_cast(half8, b), c, 0, 0, 0);
}

// ---------------------------------------------------------------------------
// Pack fp32 weights into fp16 MFMA B-fragment chunk order.
// chunk(kt, nt, lane)[i] = W[kt*32 + (lane>>4)*8 + i][nt*16 + (lane&15)]
//   WA = [wrec11; wrec12] (K=1024)  chunks [0, 65536)
//   WB = [wrec21; wrec22] (K=1024)  chunks [65536, 131072)
//   WO = wo padded to N=16 (K=512)  chunks [131072, 132096)
// ---------------------------------------------------------------------------
__global__ void pack_weights(const float* __restrict__ w11, const float* __restrict__ w12,
                             const float* __restrict__ w21, const float* __restrict__ w22,
                             const float* __restrict__ wo, unsigned short* __restrict__ dst) {
  int idx = blockIdx.x * 256 + threadIdx.x;
  if (idx < 131072) {
    int which = idx >> 16;
    int c0 = idx & 65535;
    int kt = c0 >> 11, rem = c0 & 2047;
    int nt = rem >> 6, lane = rem & 63;
    const float* wlo = which ? w21 : w11;   // k < 512  (multiplies tanh(h1))
    const float* whi = which ? w22 : w12;   // k >= 512 (multiplies tanh(h2))
    unsigned short* p = dst + (size_t)idx * 8;
    int n = nt * 16 + (lane & 15);
    int kb = kt * 32 + ((lane >> 4) & 3) * 8;
#pragma unroll
    for (int i = 0; i < 8; ++i) {
      int k = kb + i;
      float v = (k < HH) ? wlo[k * HH + n] : whi[(k - HH) * HH + n];
      p[i] = f2h(v);
    }
  } else if (idx < 132096) {
    int c0 = idx - 131072;
    int kt = c0 >> 6, lane = c0 & 63;
    unsigned short* p = dst + (size_t)131072 * 8 + (size_t)c0 * 8;
    int n = lane & 15;
    int kb = kt * 32 + ((lane >> 4) & 3) * 8;
#pragma unroll
    for (int i = 0; i < 8; ++i) {
      float v = (n < 3) ? wo[(kb + i) * 3 + n] : 0.0f;
      p[i] = f2h(v);
    }
  }
}

// zero pub1+pub2 each launch (tag 0 == initial state h=0, graph-replay safe)
__global__ void zero_ws(int* __restrict__ p, int n) {
  for (int i = blockIdx.x * 256 + threadIdx.x; i < n; i += gridDim.x * 256)
    p[i] = 0;
}

// ---------------------------------------------------------------------------
// Decoupled wave-agent RNN. 64 blocks = NSLICE(8) x NGROUP(8), 4 waves each;
// every wave is an independent agent owning a 16-col slice (nt = slice*4+w).
// NO __syncthreads in the t-loop, NO LDS in the sync path: each wave polls
// ALL 16 kt chunks of the tagged pub words straight into registers, unpacks
// in-register to its MFMA A-fragments, computes, publishes. Tag-in-data
// (word = tag<<16 | fp16) makes producer stores self-announcing.
// Per step:  A: W11xT1(regs) | poll pub2(tag==t)->T2 regs | W12xT2 |
//               h1 update | publish pub1 tag t+1
//            B: W22xT2 | poll pub1(tag==t+1)->T1 regs | W21xT1 |
//               h2 update | publish pub2 tag t+1
// WAR-safe: tag t+2 writes require all agents published tag t+1, which
// data-dependence places after their tag-t+1 reads. Tags are exact (==).
// ---------------------------------------------------------------------------
__global__ __launch_bounds__(256, 1)
void rnn_main(const float* __restrict__ x, const float* __restrict__ wi_stim,
              const float* __restrict__ wi_ctx, const float* __restrict__ noise1,
              const float* __restrict__ noise2, char* __restrict__ ws,
              float* __restrict__ out) {
  __shared__ __align__(16) unsigned short WOlds[16 * 512];  // wo B-chunks only

  const int tid = threadIdx.x;
  const int w = tid >> 6, lane = tid & 63;
  const int c16 = lane & 15, kh = lane >> 4;
  const int g = blockIdx.x & (NGROUP - 1);
  const int slice = blockIdx.x >> 3;
  const int nt = slice * 4 + w;          // n-tile 0..31
  const int n0 = nt * 16;
  const int b0 = g * 16;
  const int lrow0 = kh * 4;

  const short8* __restrict__ WC = (const short8*)ws;
  unsigned* __restrict__ pub1 = (unsigned*)(ws + PUB1_B) + g * 8192;
  unsigned* __restrict__ pub2 = (unsigned*)(ws + PUB2_B) + g * 8192;

  // ---- init: wo fragments to LDS (read-only thereafter) ----
#pragma unroll
  for (int c = 0; c < 4; ++c) {
    int kt = w * 4 + c;
    short8 v = WC[131072 + kt * 64 + lane];
    *(short8*)&WOlds[kt * 512 + lane * 8] = v;
  }

  float wis[3], wic[2];
#pragma unroll
  for (int c = 0; c < 3; ++c) wis[c] = wi_stim[c * HH + n0 + c16];
#pragma unroll
  for (int c = 0; c < 2; ++c) wic[c] = wi_ctx[c * HH + n0 + c16];

  float h1[4] = {0, 0, 0, 0}, h2[4] = {0, 0, 0, 0};

  // persistent A-fragment registers: t1f = tanh(h1[t]), t2f = tanh(h2[t])
  short8 t1f[16], t2f[16];
  short8 z = {0, 0, 0, 0, 0, 0, 0, 0};
#pragma unroll
  for (int kt = 0; kt < 16; ++kt) { t1f[kt] = z; t2f[kt] = z; }

  // publish address components: value (row=lrow0+r, col=n0+c16) -> word slot
  const int kt_p = nt >> 1;
  const int hi = (((nt & 1) * 16) + c16) >> 3;
  const int ci = c16 & 7;
  const int pslot = kt_p * 512 + (lrow0 + hi * 16) * 8 + ci;  // +r*8

  const short8* __restrict__ WAp = WC + nt * 64 + lane;           // +kt*2048
  const short8* __restrict__ WBp = WC + 65536 + nt * 64 + lane;

  // poll all 16 kt fragments (8 tagged u32 each at [kt*512 + lane*8 + j]);
  // batch-load into regs, tag-check, retry until all fresh, then unpack.
  auto poll_frags = [&](const unsigned* pubw, short8* frag, unsigned exp) {
    unsigned rw[16][8];
    bool ok;
    do {
      ok = true;
#pragma unroll
      for (int kt = 0; kt < 16; ++kt) {
        const unsigned long long* src =
            (const unsigned long long*)(pubw + kt * 512) + lane * 4;
#pragma unroll
        for (int j = 0; j < 4; ++j) {
          unsigned long long v = __hip_atomic_load(&src[j], __ATOMIC_RELAXED,
                                                   __HIP_MEMORY_SCOPE_AGENT);
          rw[kt][2 * j]     = (unsigned)v;
          rw[kt][2 * j + 1] = (unsigned)(v >> 32);
        }
      }
#pragma unroll
      for (int kt = 0; kt < 16; ++kt)
#pragma unroll
        for (int j = 0; j < 8; ++j) ok &= ((rw[kt][j] >> 16) >= exp);
      if (!__all(ok)) { __builtin_amdgcn_s_sleep(1); ok = false; }
    } while (!ok);
#pragma unroll
    for (int kt = 0; kt < 16; ++kt) {
      u32x4 p;
#pragma unroll
      for (int q = 0; q < 4; ++q)
        p[q] = (rw[kt][2 * q + 1] << 16) | (rw[kt][2 * q] & 0xffffu);
      frag[kt] = __builtin_bit_cast(short8, p);
    }
  };

  __syncthreads();   // WOlds ready; the ONLY block barrier

  for (int t = 0; t < TT; ++t) {
    const unsigned tagN = (unsigned)(t + 1) << 16;

    // per-step inputs (issued early; latency hides under MFMA/poll)
    float xv[4][5];
#pragma unroll
    for (int r = 0; r < 4; ++r)
#pragma unroll
      for (int c = 0; c < 5; ++c)
        xv[r][c] = x[((size_t)(b0 + lrow0 + r) * TT + t) * 5 + c];
    float n1v[4], n2v[4];
#pragma unroll
    for (int r = 0; r < 4; ++r) {
      size_t rowoff = ((size_t)t * BB + b0 + lrow0 + r) * HH + n0 + c16;
      n1v[r] = noise1[rowoff];
      n2v[r] = noise2[rowoff];
    }

    // ================= phase A =================
    f32x4 aA = {0, 0, 0, 0}, aB = {0, 0, 0, 0};
#pragma unroll
    for (int kt = 0; kt < 16; ++kt)      // W11 x T1 (register-stable)
      aA = mfma16(t1f[kt], WAp[kt * 2048], aA);
    poll_frags(pub2, t2f, (unsigned)t);  // tanh(h2[t]) -> regs
#pragma unroll
    for (int kt = 0; kt < 16; ++kt)      // W12 x T2
      aB = mfma16(t2f[kt], WAp[(16 + kt) * 2048], aB);

    // rotated output for step t-1: out[t-1] = tanh(h2[t]) @ wo
    if (t > 0 && slice == ((t - 1) & 7) && w == 0) {
      f32x4 ao = {0, 0, 0, 0};
#pragma unroll
      for (int kt = 0; kt < 16; ++kt) {
        short8 bo = *(const short8*)&WOlds[kt * 512 + lane * 8];
        ao = mfma16(t2f[kt], bo, ao);
      }
      if (c16 < 3) {
#pragma unroll
        for (int r = 0; r < 4; ++r)
          out[((size_t)(b0 + lrow0 + r) * TT + (t - 1)) * 3 + c16] = ao[r];
      }
    }

    unsigned short tp[4];
#pragma unroll
    for (int r = 0; r < 4; ++r) {
      float pre = aA[r] + aB[r]
                + wis[0] * xv[r][0] + wis[1] * xv[r][1] + wis[2] * xv[r][2]
                + NOISE_S * n1v[r];
      float h = (1.0f - ALPHA) * h1[r] + ALPHA * pre;
      h1[r] = h;
      tp[r] = f2h(fast_tanh(h));
    }
#pragma unroll
    for (int r = 0; r < 4; ++r)
      __hip_atomic_store(&pub1[pslot + r * 8], tagN | tp[r],
                         __ATOMIC_RELAXED, __HIP_MEMORY_SCOPE_AGENT);

    // ================= phase B =================
    f32x4 bA = {0, 0, 0, 0}, bB = {0, 0, 0, 0};
#pragma unroll
    for (int kt = 0; kt < 16; ++kt)      // W22 x T2 (register-stable)
      bB = mfma16(t2f[kt], WBp[(16 + kt) * 2048], bB);
    poll_frags(pub1, t1f, (unsigned)(t + 1));  // fresh tanh(h1[t+1]) -> regs
#pragma unroll
    for (int kt = 0; kt < 16; ++kt)      // W21 x fresh T1
      bA = mfma16(t1f[kt], WBp[kt * 2048], bA);
#pragma unroll
    for (int r = 0; r < 4; ++r) {
      float pre = bA[r] + bB[r]
                + wic[0] * xv[r][3] + wic[1] * xv[r][4]
                + NOISE_S * n2v[r];
      float h = (1.0f - ALPHA) * h2[r] + ALPHA * pre;
      h2[r] = h;
      tp[r] = f2h(fast_tanh(h));
    }
#pragma unroll
    for (int r = 0; r < 4; ++r)
      __hip_atomic_store(&pub2[pslot + r * 8], tagN | tp[r],
                         __ATOMIC_RELAXED, __HIP_MEMORY_SCOPE_AGENT);
  }

  // ---- final output: out[TT-1] = tanh(h2[TT]) @ wo ----
  if (slice == ((TT - 1) & 7) && w == 0) {
    poll_frags(pub2, t2f, (unsigned)TT);
    f32x4 ao = {0, 0, 0, 0};
#pragma unroll
    for (int kt = 0; kt < 16; ++kt) {
      short8 bo = *(const short8*)&WOlds[kt * 512 + lane * 8];
      ao = mfma16(t2f[kt], bo, ao);
    }
    if (c16 < 3) {
#pragma unroll
      for (int r = 0; r < 4; ++r)
        out[((size_t)(b0 + lrow0 + r) * TT + (TT - 1)) * 3 + c16] = ao[r];
    }
  }
}

extern "C" void kernel_launch(void* const* d_in, const int* in_sizes, int n_in,
                              void* d_out, int out_size, void* d_ws, size_t ws_size,
                              hipStream_t stream) {
  const float* x       = (const float*)d_in[0];
  const float* wi_stim = (const float*)d_in[1];
  const float* w11     = (const float*)d_in[2];
  const float* wi_ctx  = (const float*)d_in[3];
  const float* w22     = (const float*)d_in[4];
  const float* w12     = (const float*)d_in[5];
  const float* w21     = (const float*)d_in[6];
  const float* wo      = (const float*)d_in[7];
  const float* n1      = (const float*)d_in[8];
  const float* n2      = (const float*)d_in[9];
  char* ws = (char*)d_ws;                  // needs ~2.7 MB

  int nz = (NGROUP * 32768 * 2) / 4;       // pub1+pub2 words
  zero_ws<<<64, 256, 0, stream>>>((int*)(ws + PUB1_B), nz);
  pack_weights<<<516, 256, 0, stream>>>(w11, w12, w21, w22, wo,
                                        (unsigned short*)ws);
  rnn_main<<<NSLICE * NGROUP, 256, 0, stream>>>(x, wi_stim, wi_ctx, n1, n2, ws,
                                                (float*)d_out);
}

// Round 13
// 6868.558 us; speedup vs baseline: 1.5582x; 1.5582x over previous
//
#include <hip/hip_runtime.h>
#include <hip/hip_bf16.h>

#define TT 512
#define BB 128
#define HH 512
#define NGROUP 8          // batch groups, 16 rows each
#define NSLICE 8          // col-slice blocks per group (4 waves x 16 cols each)
#define ALPHA 0.1f
#define NOISE_S 0.02f

typedef __attribute__((ext_vector_type(8))) short short8;
typedef __attribute__((ext_vector_type(8))) _Float16 half8;
typedef __attribute__((ext_vector_type(4))) float f32x4;

// ---- workspace layout (bytes) ----
#define WPACK_CH 132096                       // 16B chunks of packed weights
#define PUB1_B (WPACK_CH * 16)                // tanh1 pub: [NGROUP][8192] u32 words
#define PUB2_B (PUB1_B + NGROUP * 32768)      // tanh2 pub: [NGROUP][8192] u32 words
// word = (step_tag << 16) | fp16_bits ; word idx = kt*512 + srow*8 + j

__device__ __forceinline__ unsigned short f2h(float f) {
  return __builtin_bit_cast(unsigned short, (_Float16)f);  // RNE
}

__device__ __forceinline__ float fast_tanh(float x) {
  float e = __builtin_amdgcn_exp2f(x * 2.8853900817779268f);
  return 1.0f - 2.0f * __builtin_amdgcn_rcpf(e + 1.0f);
}

__device__ __forceinline__ f32x4 mfma16(short8 a, short8 b, f32x4 c) {
  return __builtin_amdgcn_mfma_f32_16x16x32_f16(
      __builtin_bit_cast(half8, a), __builtin_bit_cast(half8, b), c, 0, 0, 0);
}

// ---------------------------------------------------------------------------
// Pack fp32 weights into fp16 MFMA B-fragment chunk order.
// chunk(kt, nt, lane)[i] = W[kt*32 + (lane>>4)*8 + i][nt*16 + (lane&15)]
//   WA = [wrec11; wrec12] (K=1024)  chunks [0, 65536)
//   WB = [wrec21; wrec22] (K=1024)  chunks [65536, 131072)
//   WO = wo padded to N=16 (K=512)  chunks [131072, 132096)
// ---------------------------------------------------------------------------
__global__ void pack_weights(const float* __restrict__ w11, const float* __restrict__ w12,
                             const float* __restrict__ w21, const float* __restrict__ w22,
                             const float* __restrict__ wo, unsigned short* __restrict__ dst) {
  int idx = blockIdx.x * 256 + threadIdx.x;
  if (idx < 131072) {
    int which = idx >> 16;
    int c0 = idx & 65535;
    int kt = c0 >> 11, rem = c0 & 2047;
    int nt = rem >> 6, lane = rem & 63;
    const float* wlo = which ? w21 : w11;   // k < 512  (multiplies tanh(h1))
    const float* whi = which ? w22 : w12;   // k >= 512 (multiplies tanh(h2))
    unsigned short* p = dst + (size_t)idx * 8;
    int n = nt * 16 + (lane & 15);
    int kb = kt * 32 + ((lane >> 4) & 3) * 8;
#pragma unroll
    for (int i = 0; i < 8; ++i) {
      int k = kb + i;
      float v = (k < HH) ? wlo[k * HH + n] : whi[(k - HH) * HH + n];
      p[i] = f2h(v);
    }
  } else if (idx < 132096) {
    int c0 = idx - 131072;
    int kt = c0 >> 6, lane = c0 & 63;
    unsigned short* p = dst + (size_t)131072 * 8 + (size_t)c0 * 8;
    int n = lane & 15;
    int kb = kt * 32 + ((lane >> 4) & 3) * 8;
#pragma unroll
    for (int i = 0; i < 8; ++i) {
      float v = (n < 3) ? wo[(kb + i) * 3 + n] : 0.0f;
      p[i] = f2h(v);
    }
  }
}

// zero pub1+pub2 each launch (tag 0 == initial state h=0, graph-replay safe)
__global__ void zero_ws(int* __restrict__ p, int n) {
  for (int i = blockIdx.x * 256 + threadIdx.x; i < n; i += gridDim.x * 256)
    p[i] = 0;
}

// ---------------------------------------------------------------------------
// Sliced persistent RNN; tag-in-data sync with PRE-ISSUED poll loads.
// Grid: 64 blocks = NSLICE(8) x NGROUP(8); 4 waves x 16 cols each.
// Each wave polls only its quarter (4 kt chunks) and shares via LDS (one
// __syncthreads per phase). The poll loads for the NEXT sync point are
// issued immediately after the preceding publish, so their round trip
// overlaps the stable-half MFMA cluster + weight streaming.
// Phase A (step t): [pv2 in flight] W11xT1 -> check pv2 (tag>=t, retry) ->
//   stage T2 -> barrier -> W12xT2 (+rotated out[t-1]) -> h1 update ->
//   publish pub1 tag t+1 -> pre-issue pv1.
// Phase B: W22xT2 -> check pv1 (tag>=t+1) -> stage T1' -> barrier ->
//   W21xT1' -> h2 update -> publish pub2 tag t+1 -> pre-issue pv2.
// WAR-safe as before: tags never advance past a pending reader.
// ---------------------------------------------------------------------------
__global__ __launch_bounds__(256, 1)
void rnn_main(const float* __restrict__ x, const float* __restrict__ wi_stim,
              const float* __restrict__ wi_ctx, const float* __restrict__ noise1,
              const float* __restrict__ noise2, char* __restrict__ ws,
              float* __restrict__ out) {
  __shared__ __align__(16) unsigned short T1buf[16 * 512];  // tanh(h1) A-chunks
  __shared__ __align__(16) unsigned short T2buf[16 * 512];  // tanh(h2) A-chunks
  __shared__ __align__(16) unsigned short WOlds[16 * 512];  // wo B-chunks
  __shared__ float xstage[2][16][5];

  const int tid = threadIdx.x;
  const int w = tid >> 6, lane = tid & 63;
  const int c16 = lane & 15, kh = lane >> 4;
  const int g = blockIdx.x & (NGROUP - 1);
  const int slice = blockIdx.x >> 3;
  const int nt = slice * 4 + w;          // n-tile 0..31
  const int n0 = nt * 16;
  const int b0 = g * 16;
  const int lrow0 = kh * 4;

  const short8* __restrict__ WC = (const short8*)ws;
  unsigned* __restrict__ pub1 = (unsigned*)(ws + PUB1_B) + g * 8192;
  unsigned* __restrict__ pub2 = (unsigned*)(ws + PUB2_B) + g * 8192;

  // ---- init LDS ----
  short8 z = {0, 0, 0, 0, 0, 0, 0, 0};
  for (int i = tid; i < 1024; i += 256) {
    ((short8*)T1buf)[i] = z;             // tanh(0) = 0
    ((short8*)T2buf)[i] = z;
  }
#pragma unroll
  for (int c = 0; c < 4; ++c) {          // wo fragments to LDS (all blocks)
    int kt = w * 4 + c;
    short8 v = WC[131072 + kt * 64 + lane];
    *(short8*)&WOlds[kt * 512 + lane * 8] = v;
  }
  if (tid < 80) {
    int b = tid / 5, c = tid % 5;
    xstage[0][b][c] = x[((size_t)(b0 + b) * TT + 0) * 5 + c];
  }

  float wis[3], wic[2];
#pragma unroll
  for (int c = 0; c < 3; ++c) wis[c] = wi_stim[c * HH + n0 + c16];
#pragma unroll
  for (int c = 0; c < 2; ++c) wic[c] = wi_ctx[c * HH + n0 + c16];

  float h1[4] = {0, 0, 0, 0}, h2[4] = {0, 0, 0, 0};

  // publish address components: value (row=lrow0+r, col=n0+c16) -> word slot
  const int kt_p = nt >> 1;
  const int hi = (((nt & 1) * 16) + c16) >> 3;
  const int ci = c16 & 7;
  const int pslot = kt_p * 512 + (lrow0 + hi * 16) * 8 + ci;  // +r*8

  const short8* __restrict__ WAp = WC + nt * 64 + lane;           // +kt*2048
  const short8* __restrict__ WBp = WC + 65536 + nt * 64 + lane;

  unsigned long long pv1[4][4], pv2[4][4];   // in-flight poll buffers

  // issue this wave's quarter (4 chunks x 4 u64) of pubw into pv
  auto issue_poll = [&](const unsigned* pubw, unsigned long long (*pv)[4]) {
#pragma unroll
    for (int c = 0; c < 4; ++c) {
      const unsigned long long* src =
          (const unsigned long long*)(pubw + ((w * 4 + c) << 9)) + lane * 4;
#pragma unroll
      for (int j = 0; j < 4; ++j)
        pv[c][j] = __hip_atomic_load(&src[j], __ATOMIC_RELAXED,
                                     __HIP_MEMORY_SCOPE_AGENT);
    }
  };

  // check pre-issued pv; retry until all tags >= exp; unpack into LDS
  auto finish_poll = [&](const unsigned* pubw, unsigned long long (*pv)[4],
                         unsigned short* Tbuf, unsigned exp) {
    for (;;) {
      bool ok = true;
#pragma unroll
      for (int c = 0; c < 4; ++c)
#pragma unroll
        for (int j = 0; j < 4; ++j) {
          ok &= (((unsigned)(pv[c][j] >> 16) & 0xffffu) >= exp);
          ok &= ((unsigned)(pv[c][j] >> 48) >= exp);
        }
      if (ok) break;
      issue_poll(pubw, pv);
    }
    __builtin_amdgcn_sched_barrier(0);
    asm volatile("" ::: "memory");
#pragma unroll
    for (int c = 0; c < 4; ++c) {
      unsigned long long u0 = (pv[c][0] & 0xffffull)
                            | (((pv[c][0] >> 32) & 0xffffull) << 16)
                            | ((pv[c][1] & 0xffffull) << 32)
                            | (((pv[c][1] >> 32) & 0xffffull) << 48);
      unsigned long long u1 = (pv[c][2] & 0xffffull)
                            | (((pv[c][2] >> 32) & 0xffffull) << 16)
                            | ((pv[c][3] & 0xffffull) << 32)
                            | (((pv[c][3] >> 32) & 0xffffull) << 48);
      *(unsigned long long*)&Tbuf[(w * 4 + c) * 512 + lane * 8] = u0;
      *(unsigned long long*)&Tbuf[(w * 4 + c) * 512 + lane * 8 + 4] = u1;
    }
  };

  __syncthreads();
  issue_poll(pub2, pv2);                 // t=0 phase A poll in flight
  __builtin_amdgcn_sched_barrier(0);

  for (int t = 0; t < TT; ++t) {
    const int buf = t & 1;
    const unsigned tagN = (unsigned)(t + 1) << 16;

    // per-step inputs (early issue; consumed in epilogues)
    float n1v[4], n2v[4];
#pragma unroll
    for (int r = 0; r < 4; ++r) {
      size_t rowoff = ((size_t)t * BB + b0 + lrow0 + r) * HH + n0 + c16;
      n1v[r] = noise1[rowoff];
      n2v[r] = noise2[rowoff];
    }

    // ================= phase A =================
    f32x4 aA = {0, 0, 0, 0}, aB = {0, 0, 0, 0};
#pragma unroll
    for (int kt = 0; kt < 16; ++kt) {    // W11 x T1 (poll loads in flight)
      short8 a1 = *(const short8*)&T1buf[kt * 512 + lane * 8];
      aA = mfma16(a1, WAp[kt * 2048], aA);
    }
    finish_poll(pub2, pv2, T2buf, (unsigned)t);   // tanh(h2[t])
    __syncthreads();
#pragma unroll
    for (int kt = 0; kt < 16; ++kt) {    // W12 x T2
      short8 a2 = *(const short8*)&T2buf[kt * 512 + lane * 8];
      aB = mfma16(a2, WAp[(16 + kt) * 2048], aB);
    }

    // rotated output for step t-1: out[t-1] = tanh(h2[t]) @ wo
    if (t > 0 && slice == ((t - 1) & 7) && w == 0) {
      f32x4 ao = {0, 0, 0, 0};
#pragma unroll
      for (int kt = 0; kt < 16; ++kt) {
        short8 a2 = *(const short8*)&T2buf[kt * 512 + lane * 8];
        short8 bo = *(const short8*)&WOlds[kt * 512 + lane * 8];
        ao = mfma16(a2, bo, ao);
      }
      if (c16 < 3) {
#pragma unroll
        for (int r = 0; r < 4; ++r)
          out[((size_t)(b0 + lrow0 + r) * TT + (t - 1)) * 3 + c16] = ao[r];
      }
    }

    unsigned short tp[4];
#pragma unroll
    for (int r = 0; r < 4; ++r) {
      float pre = aA[r] + aB[r]
                + wis[0] * xstage[buf][lrow0 + r][0]
                + wis[1] * xstage[buf][lrow0 + r][1]
                + wis[2] * xstage[buf][lrow0 + r][2]
                + NOISE_S * n1v[r];
      float h = (1.0f - ALPHA) * h1[r] + ALPHA * pre;
      h1[r] = h;
      tp[r] = f2h(fast_tanh(h));
    }
#pragma unroll
    for (int r = 0; r < 4; ++r)
      __hip_atomic_store(&pub1[pslot + r * 8], tagN | tp[r],
                         __ATOMIC_RELAXED, __HIP_MEMORY_SCOPE_AGENT);
    issue_poll(pub1, pv1);               // phase-B poll in flight
    __builtin_amdgcn_sched_barrier(0);

    // ================= phase B =================
    f32x4 bA = {0, 0, 0, 0}, bB = {0, 0, 0, 0};
#pragma unroll
    for (int kt = 0; kt < 16; ++kt) {    // W22 x T2 (poll loads in flight)
      short8 a2 = *(const short8*)&T2buf[kt * 512 + lane * 8];
      bB = mfma16(a2, WBp[(16 + kt) * 2048], bB);
    }
    finish_poll(pub1, pv1, T1buf, (unsigned)(t + 1));  // fresh tanh(h1')
    if (t + 1 < TT && tid < 80) {
      int b = tid / 5, c = tid % 5;
      xstage[buf ^ 1][b][c] = x[((size_t)(b0 + b) * TT + (t + 1)) * 5 + c];
    }
    __syncthreads();
#pragma unroll
    for (int kt = 0; kt < 16; ++kt) {    // W21 x fresh tanh(h1')
      short8 a1 = *(const short8*)&T1buf[kt * 512 + lane * 8];
      bA = mfma16(a1, WBp[kt * 2048], bA);
    }
#pragma unroll
    for (int r = 0; r < 4; ++r) {
      float pre = bA[r] + bB[r]
                + wic[0] * xstage[buf][lrow0 + r][3]
                + wic[1] * xstage[buf][lrow0 + r][4]
                + NOISE_S * n2v[r];
      float h = (1.0f - ALPHA) * h2[r] + ALPHA * pre;
      h2[r] = h;
      tp[r] = f2h(fast_tanh(h));
    }
#pragma unroll
    for (int r = 0; r < 4; ++r)
      __hip_atomic_store(&pub2[pslot + r * 8], tagN | tp[r],
                         __ATOMIC_RELAXED, __HIP_MEMORY_SCOPE_AGENT);
    issue_poll(pub2, pv2);               // next phase-A poll in flight
    __builtin_amdgcn_sched_barrier(0);
  }

  // ---- final output: out[TT-1] = tanh(h2[TT]) @ wo ----
  if (slice == ((TT - 1) & 7)) {
    finish_poll(pub2, pv2, T2buf, (unsigned)TT);
    __syncthreads();
    if (w == 0) {
      f32x4 ao = {0, 0, 0, 0};
#pragma unroll
      for (int kt = 0; kt < 16; ++kt) {
        short8 a2 = *(const short8*)&T2buf[kt * 512 + lane * 8];
        short8 bo = *(const short8*)&WOlds[kt * 512 + lane * 8];
        ao = mfma16(a2, bo, ao);
      }
      if (c16 < 3) {
#pragma unroll
        for (int r = 0; r < 4; ++r)
          out[((size_t)(b0 + lrow0 + r) * TT + (TT - 1)) * 3 + c16] = ao[r];
      }
    }
  }
}

extern "C" void kernel_launch(void* const* d_in, const int* in_sizes, int n_in,
                              void* d_out, int out_size, void* d_ws, size_t ws_size,
                              hipStream_t stream) {
  const float* x       = (const float*)d_in[0];
  const float* wi_stim = (const float*)d_in[1];
  const float* w11     = (const float*)d_in[2];
  const float* wi_ctx  = (const float*)d_in[3];
  const float* w22     = (const float*)d_in[4];
  const float* w12     = (const float*)d_in[5];
  const float* w21     = (const float*)d_in[6];
  const float* wo      = (const float*)d_in[7];
  const float* n1      = (const float*)d_in[8];
  const float* n2      = (const float*)d_in[9];
  char* ws = (char*)d_ws;                  // needs ~2.7 MB

  int nz = (NGROUP * 32768 * 2) / 4;       // pub1+pub2 words
  zero_ws<<<64, 256, 0, stream>>>((int*)(ws + PUB1_B), nz);
  pack_weights<<<516, 256, 0, stream>>>(w11, w12, w21, w22, wo,
                                        (unsigned short*)ws);
  rnn_main<<<NSLICE * NGROUP, 256, 0, stream>>>(x, wi_stim, wi_ctx, n1, n2, ws,
                                                (float*)d_out);
}

// Round 15
// 4824.288 us; speedup vs baseline: 2.2184x; 1.4237x over previous
//
#include <hip/hip_runtime.h>
#include <hip/hip_bf16.h>

#define TT 512
#define BB 128
#define HH 512
#define NGROUP 8          // batch groups, 16 rows each
#define NSLICE 8          // col-slice blocks per group (4 waves x 16 cols each)
#define ALPHA 0.1f
#define NOISE_S 0.02f

typedef __attribute__((ext_vector_type(8))) short short8;
typedef __attribute__((ext_vector_type(8))) _Float16 half8;
typedef __attribute__((ext_vector_type(4))) float f32x4;

// ---- workspace layout (bytes) ----
#define WPACK_CH 132096                        // 16B chunks of packed weights
#define PUBS1_B (WPACK_CH * 16)                // slow pub tanh1 (agent/MALL)
#define PUBS2_B (PUBS1_B + NGROUP * 32768)     // slow pub tanh2
#define PUBF1_B (PUBS2_B + NGROUP * 32768)     // fast pub tanh1 (sc0/local L2)
#define PUBF2_B (PUBF1_B + NGROUP * 32768)     // fast pub tanh2
#define XCD_B   (PUBF2_B + NGROUP * 32768)     // xcdinfo: [NGROUP][8] int
// pub word = (step_tag << 16) | fp16_bits ; word idx = kt*512 + srow*8 + j

__device__ __forceinline__ unsigned short f2h(float f) {
  return __builtin_bit_cast(unsigned short, (_Float16)f);  // RNE
}

__device__ __forceinline__ float fast_tanh(float x) {
  float e = __builtin_amdgcn_exp2f(x * 2.8853900817779268f);
  return 1.0f - 2.0f * __builtin_amdgcn_rcpf(e + 1.0f);
}

__device__ __forceinline__ f32x4 mfma16(short8 a, short8 b, f32x4 c) {
  return __builtin_amdgcn_mfma_f32_16x16x32_f16(
      __builtin_bit_cast(half8, a), __builtin_bit_cast(half8, b), c, 0, 0, 0);
}

// ---------------------------------------------------------------------------
// Pack fp32 weights into fp16 MFMA B-fragment chunk order.
// chunk(kt, nt, lane)[i] = W[kt*32 + (lane>>4)*8 + i][nt*16 + (lane&15)]
//   WA = [wrec11; wrec12] (K=1024)  chunks [0, 65536)
//   WB = [wrec21; wrec22] (K=1024)  chunks [65536, 131072)
//   WO = wo padded to N=16 (K=512)  chunks [131072, 132096)
// ---------------------------------------------------------------------------
__global__ void pack_weights(const float* __restrict__ w11, const float* __restrict__ w12,
                             const float* __restrict__ w21, const float* __restrict__ w22,
                             const float* __restrict__ wo, unsigned short* __restrict__ dst) {
  int idx = blockIdx.x * 256 + threadIdx.x;
  if (idx < 131072) {
    int which = idx >> 16;
    int c0 = idx & 65535;
    int kt = c0 >> 11, rem = c0 & 2047;
    int nt = rem >> 6, lane = rem & 63;
    const float* wlo = which ? w21 : w11;   // k < 512  (multiplies tanh(h1))
    const float* whi = which ? w22 : w12;   // k >= 512 (multiplies tanh(h2))
    unsigned short* p = dst + (size_t)idx * 8;
    int n = nt * 16 + (lane & 15);
    int kb = kt * 32 + ((lane >> 4) & 3) * 8;
#pragma unroll
    for (int i = 0; i < 8; ++i) {
      int k = kb + i;
      float v = (k < HH) ? wlo[k * HH + n] : whi[(k - HH) * HH + n];
      p[i] = f2h(v);
    }
  } else if (idx < 132096) {
    int c0 = idx - 131072;
    int kt = c0 >> 6, lane = c0 & 63;
    unsigned short* p = dst + (size_t)131072 * 8 + (size_t)c0 * 8;
    int n = lane & 15;
    int kb = kt * 32 + ((lane >> 4) & 3) * 8;
#pragma unroll
    for (int i = 0; i < 8; ++i) {
      float v = (n < 3) ? wo[(kb + i) * 3 + n] : 0.0f;
      p[i] = f2h(v);
    }
  }
}

// zero all pub regions each launch (tag 0 == initial h=0 state); kernel
// boundary flushes dirty L2 so zeros are globally visible in rnn_main.
__global__ void zero_ws(int* __restrict__ p, int n) {
  for (int i = blockIdx.x * 256 + threadIdx.x; i < n; i += gridDim.x * 256)
    p[i] = 0;
}
__global__ void init_xcd(int* __restrict__ p) {
  p[threadIdx.x] = -1;                   // 64 = NGROUP*8
}

// ---------------------------------------------------------------------------
// Sliced persistent RNN; tag-in-data sync with DUAL-PATH publish:
//   pubS: agent-scope stores/loads (MALL coherence point) -- always correct.
//   pubF: plain sc0 stores (write-through -> local L2) polled with sc0 loads,
//         used ONLY when all 8 blocks of the group verified on one XCD, and
//         ONLY via a bounded probe (128 iter) with sticky per-wave fallback.
// No unbounded spin exists on the unverified-cache-bit path => hang-proof.
// Grid: 64 blocks = NSLICE(8) x NGROUP(8); g = blockIdx&7 (round-robin puts
// a group's blocks on one XCD; verified in-kernel via HW_REG_XCC_ID).
// Phase A (t): W11xT1 -> poll T2(tag>=t) -> stage -> barrier -> W12xT2
//   (+rotated out[t-1]) -> h1 update -> publish tanh(h1') tag t+1.
// Phase B: W22xT2 -> poll T1'(tag>=t+1) -> stage -> barrier -> W21xT1' ->
//   h2 update -> publish tanh(h2') tag t+1.
// WAR-safe: tags never advance past a pending reader (publish follows the
// staging of the peer buffer by dataflow).
// ---------------------------------------------------------------------------
__global__ __launch_bounds__(256, 1)
void rnn_main(const float* __restrict__ x, const float* __restrict__ wi_stim,
              const float* __restrict__ wi_ctx, const float* __restrict__ noise1,
              const float* __restrict__ noise2, char* __restrict__ ws,
              float* __restrict__ out) {
  __shared__ __align__(16) unsigned short T1buf[16 * 512];  // tanh(h1) A-chunks
  __shared__ __align__(16) unsigned short T2buf[16 * 512];  // tanh(h2) A-chunks
  __shared__ __align__(16) unsigned short WOlds[16 * 512];  // wo B-chunks
  __shared__ float xstage[2][16][5];

  const int tid = threadIdx.x;
  const int w = tid >> 6, lane = tid & 63;
  const int c16 = lane & 15, kh = lane >> 4;
  const int g = blockIdx.x & (NGROUP - 1);
  const int slice = blockIdx.x >> 3;
  const int nt = slice * 4 + w;          // n-tile 0..31
  const int n0 = nt * 16;
  const int b0 = g * 16;
  const int lrow0 = kh * 4;

  const short8* __restrict__ WC = (const short8*)ws;
  unsigned* __restrict__ pubS1 = (unsigned*)(ws + PUBS1_B) + g * 8192;
  unsigned* __restrict__ pubS2 = (unsigned*)(ws + PUBS2_B) + g * 8192;
  unsigned* __restrict__ pubF1 = (unsigned*)(ws + PUBF1_B) + g * 8192;
  unsigned* __restrict__ pubF2 = (unsigned*)(ws + PUBF2_B) + g * 8192;
  int* __restrict__ xcdinfo = (int*)(ws + XCD_B) + g * 8;

  // ---- init LDS ----
  short8 z = {0, 0, 0, 0, 0, 0, 0, 0};
  for (int i = tid; i < 1024; i += 256) {
    ((short8*)T1buf)[i] = z;             // tanh(0) = 0
    ((short8*)T2buf)[i] = z;
  }
#pragma unroll
  for (int c = 0; c < 4; ++c) {          // wo fragments to LDS (all blocks)
    int kt = w * 4 + c;
    short8 v = WC[131072 + kt * 64 + lane];
    *(short8*)&WOlds[kt * 512 + lane * 8] = v;
  }
  if (tid < 80) {
    int b = tid / 5, c = tid % 5;
    xstage[0][b][c] = x[((size_t)(b0 + b) * TT + 0) * 5 + c];
  }

  // ---- XCD co-location check (one-time; cannot hang: stores always land) ----
  int my_xcd;
  asm volatile("s_getreg_b32 %0, hwreg(HW_REG_XCC_ID)" : "=s"(my_xcd));
  if (tid == 0)
    __hip_atomic_store(&xcdinfo[slice], my_xcd, __ATOMIC_RELAXED,
                       __HIP_MEMORY_SCOPE_AGENT);
  bool same;
  {
    int v;
    do {
      v = (lane < 8) ? __hip_atomic_load(&xcdinfo[lane], __ATOMIC_RELAXED,
                                         __HIP_MEMORY_SCOPE_AGENT)
                     : my_xcd;
    } while (!__all(v != -1));
    same = __all(v == my_xcd);           // uniform across the block
  }
  bool fastOK = same;                    // sticky per-wave

  float wis[3], wic[2];
#pragma unroll
  for (int c = 0; c < 3; ++c) wis[c] = wi_stim[c * HH + n0 + c16];
#pragma unroll
  for (int c = 0; c < 2; ++c) wic[c] = wi_ctx[c * HH + n0 + c16];

  float h1[4] = {0, 0, 0, 0}, h2[4] = {0, 0, 0, 0};

  // publish address components: value (row=lrow0+r, col=n0+c16) -> word slot
  const int kt_p = nt >> 1;
  const int hi = (((nt & 1) * 16) + c16) >> 3;
  const int ci = c16 & 7;
  const int pslot = kt_p * 512 + (lrow0 + hi * 16) * 8 + ci;  // +r*8

  const short8* __restrict__ WAp = WC + nt * 64 + lane;           // +kt*2048
  const short8* __restrict__ WBp = WC + 65536 + nt * 64 + lane;

  // publish 4 tagged words: slow (agent, always) then fast (sc0, if same-XCD)
  auto publish4 = [&](unsigned* pS, unsigned* pF, const unsigned short* tp,
                      unsigned tagN) {
#pragma unroll
    for (int r = 0; r < 4; ++r)
      __hip_atomic_store(&pS[pslot + r * 8], tagN | tp[r],
                         __ATOMIC_RELAXED, __HIP_MEMORY_SCOPE_AGENT);
    if (same) {
#pragma unroll
      for (int r = 0; r < 4; ++r) {
        unsigned word = tagN | tp[r];
        asm volatile("global_store_dword %0, %1, off sc0"
                     :: "v"((unsigned long long)(uintptr_t)&pF[pslot + r * 8]),
                        "v"(word)
                     : "memory");
      }
    }
  };

  // poll own quarter until all tags >= exp, then unpack into LDS.
  // Fast: bounded sc0 probe on pF (local L2). Slow: uncapped agent on pS.
  auto finish_poll = [&](const unsigned* pS, const unsigned* pF,
                         unsigned short* Tbuf, unsigned exp) {
    unsigned long long v[4][4];
    bool got = false;
    if (fastOK) {
      for (int it = 0; it < 128; ++it) {
#pragma unroll
        for (int c = 0; c < 4; ++c) {
          const char* base = (const char*)(pF + ((w * 4 + c) << 9)) + lane * 32;
#pragma unroll
          for (int j = 0; j < 4; ++j)
            asm volatile("global_load_dwordx2 %0, %1, off sc0"
                         : "=v"(v[c][j])
                         : "v"((unsigned long long)(uintptr_t)(base + j * 8))
                         : "memory");
        }
        asm volatile("s_waitcnt vmcnt(0)" ::: "memory");
        __builtin_amdgcn_sched_barrier(0);
        bool ok = true;
#pragma unroll
        for (int c = 0; c < 4; ++c)
#pragma unroll
          for (int j = 0; j < 4; ++j) {
            ok &= (((unsigned)(v[c][j] >> 16) & 0xffffu) >= exp);
            ok &= ((unsigned)(v[c][j] >> 48) >= exp);
          }
        if (__all(ok)) { got = true; break; }
      }
      if (!got) fastOK = false;          // sticky fallback, hang-proof
    }
    if (!got) {
      for (;;) {
#pragma unroll
        for (int c = 0; c < 4; ++c) {
          const unsigned long long* src =
              (const unsigned long long*)(pS + ((w * 4 + c) << 9)) + lane * 4;
#pragma unroll
          for (int j = 0; j < 4; ++j)
            v[c][j] = __hip_atomic_load(&src[j], __ATOMIC_RELAXED,
                                        __HIP_MEMORY_SCOPE_AGENT);
        }
        bool ok = true;
#pragma unroll
        for (int c = 0; c < 4; ++c)
#pragma unroll
          for (int j = 0; j < 4; ++j) {
            ok &= (((unsigned)(v[c][j] >> 16) & 0xffffu) >= exp);
            ok &= ((unsigned)(v[c][j] >> 48) >= exp);
          }
        if (__all(ok)) break;
        __builtin_amdgcn_s_sleep(1);
      }
    }
    __builtin_amdgcn_sched_barrier(0);
    asm volatile("" ::: "memory");
#pragma unroll
    for (int c = 0; c < 4; ++c) {
      unsigned long long u0 = (v[c][0] & 0xffffull)
                            | (((v[c][0] >> 32) & 0xffffull) << 16)
                            | ((v[c][1] & 0xffffull) << 32)
                            | (((v[c][1] >> 32) & 0xffffull) << 48);
      unsigned long long u1 = (v[c][2] & 0xffffull)
                            | (((v[c][2] >> 32) & 0xffffull) << 16)
                            | ((v[c][3] & 0xffffull) << 32)
                            | (((v[c][3] >> 32) & 0xffffull) << 48);
      *(unsigned long long*)&Tbuf[(w * 4 + c) * 512 + lane * 8] = u0;
      *(unsigned long long*)&Tbuf[(w * 4 + c) * 512 + lane * 8 + 4] = u1;
    }
  };

  __syncthreads();

  for (int t = 0; t < TT; ++t) {
    const int buf = t & 1;
    const unsigned tagN = (unsigned)(t + 1) << 16;

    // per-step inputs (early issue; consumed in epilogues)
    float n1v[4], n2v[4];
#pragma unroll
    for (int r = 0; r < 4; ++r) {
      size_t rowoff = ((size_t)t * BB + b0 + lrow0 + r) * HH + n0 + c16;
      n1v[r] = noise1[rowoff];
      n2v[r] = noise2[rowoff];
    }

    // ================= phase A =================
    f32x4 aA = {0, 0, 0, 0}, aB = {0, 0, 0, 0};
#pragma unroll
    for (int kt = 0; kt < 16; ++kt) {    // W11 x T1 (local, stable)
      short8 a1 = *(const short8*)&T1buf[kt * 512 + lane * 8];
      aA = mfma16(a1, WAp[kt * 2048], aA);
    }
    finish_poll(pubS2, pubF2, T2buf, (unsigned)t);   // tanh(h2[t])
    __syncthreads();
#pragma unroll
    for (int kt = 0; kt < 16; ++kt) {    // W12 x T2
      short8 a2 = *(const short8*)&T2buf[kt * 512 + lane * 8];
      aB = mfma16(a2, WAp[(16 + kt) * 2048], aB);
    }

    // rotated output for step t-1: out[t-1] = tanh(h2[t]) @ wo
    if (t > 0 && slice == ((t - 1) & 7) && w == 0) {
      f32x4 ao = {0, 0, 0, 0};
#pragma unroll
      for (int kt = 0; kt < 16; ++kt) {
        short8 a2 = *(const short8*)&T2buf[kt * 512 + lane * 8];
        short8 bo = *(const short8*)&WOlds[kt * 512 + lane * 8];
        ao = mfma16(a2, bo, ao);
      }
      if (c16 < 3) {
#pragma unroll
        for (int r = 0; r < 4; ++r)
          out[((size_t)(b0 + lrow0 + r) * TT + (t - 1)) * 3 + c16] = ao[r];
      }
    }

    unsigned short tp[4];
#pragma unroll
    for (int r = 0; r < 4; ++r) {
      float pre = aA[r] + aB[r]
                + wis[0] * xstage[buf][lrow0 + r][0]
                + wis[1] * xstage[buf][lrow0 + r][1]
                + wis[2] * xstage[buf][lrow0 + r][2]
                + NOISE_S * n1v[r];
      float h = (1.0f - ALPHA) * h1[r] + ALPHA * pre;
      h1[r] = h;
      tp[r] = f2h(fast_tanh(h));
    }
    publish4(pubS1, pubF1, tp, tagN);

    // ================= phase B =================
    f32x4 bA = {0, 0, 0, 0}, bB = {0, 0, 0, 0};
#pragma unroll
    for (int kt = 0; kt < 16; ++kt) {    // W22 x T2 (stable across sync)
      short8 a2 = *(const short8*)&T2buf[kt * 512 + lane * 8];
      bB = mfma16(a2, WBp[(16 + kt) * 2048], bB);
    }
    finish_poll(pubS1, pubF1, T1buf, (unsigned)(t + 1));  // fresh tanh(h1')
    if (t + 1 < TT && tid < 80) {
      int b = tid / 5, c = tid % 5;
      xstage[buf ^ 1][b][c] = x[((size_t)(b0 + b) * TT + (t + 1)) * 5 + c];
    }
    __syncthreads();
#pragma unroll
    for (int kt = 0; kt < 16; ++kt) {    // W21 x fresh tanh(h1')
      short8 a1 = *(const short8*)&T1buf[kt * 512 + lane * 8];
      bA = mfma16(a1, WBp[kt * 2048], bA);
    }
#pragma unroll
    for (int r = 0; r < 4; ++r) {
      float pre = bA[r] + bB[r]
                + wic[0] * xstage[buf][lrow0 + r][3]
                + wic[1] * xstage[buf][lrow0 + r][4]
                + NOISE_S * n2v[r];
      float h = (1.0f - ALPHA) * h2[r] + ALPHA * pre;
      h2[r] = h;
      tp[r] = f2h(fast_tanh(h));
    }
    publish4(pubS2, pubF2, tp, tagN);
  }

  // ---- final output: out[TT-1] = tanh(h2[TT]) @ wo ----
  if (slice == ((TT - 1) & 7)) {
    finish_poll(pubS2, pubF2, T2buf, (unsigned)TT);
    __syncthreads();
    if (w == 0) {
      f32x4 ao = {0, 0, 0, 0};
#pragma unroll
      for (int kt = 0; kt < 16; ++kt) {
        short8 a2 = *(const short8*)&T2buf[kt * 512 + lane * 8];
        short8 bo = *(const short8*)&WOlds[kt * 512 + lane * 8];
        ao = mfma16(a2, bo, ao);
      }
      if (c16 < 3) {
#pragma unroll
        for (int r = 0; r < 4; ++r)
          out[((size_t)(b0 + lrow0 + r) * TT + (TT - 1)) * 3 + c16] = ao[r];
      }
    }
  }
}

extern "C" void kernel_launch(void* const* d_in, const int* in_sizes, int n_in,
                              void* d_out, int out_size, void* d_ws, size_t ws_size,
                              hipStream_t stream) {
  const float* x       = (const float*)d_in[0];
  const float* wi_stim = (const float*)d_in[1];
  const float* w11     = (const float*)d_in[2];
  const float* wi_ctx  = (const float*)d_in[3];
  const float* w22     = (const float*)d_in[4];
  const float* w12     = (const float*)d_in[5];
  const float* w21     = (const float*)d_in[6];
  const float* wo      = (const float*)d_in[7];
  const float* n1      = (const float*)d_in[8];
  const float* n2      = (const float*)d_in[9];
  char* ws = (char*)d_ws;                  // needs ~3.2 MB

  int nz = (NGROUP * 32768 * 4) / 4;       // pubS1+pubS2+pubF1+pubF2 words
  zero_ws<<<64, 256, 0, stream>>>((int*)(ws + PUBS1_B), nz);
  init_xcd<<<1, 64, 0, stream>>>((int*)(ws + XCD_B));
  pack_weights<<<516, 256, 0, stream>>>(w11, w12, w21, w22, wo,
                                        (unsigned short*)ws);
  rnn_main<<<NSLICE * NGROUP, 256, 0, stream>>>(x, wi_stim, wi_ctx, n1, n2, ws,
                                                (float*)d_out);
}

// Round 16
// 4299.794 us; speedup vs baseline: 2.4890x; 1.1220x over previous
//
#include <hip/hip_runtime.h>
#include <hip/hip_bf16.h>

#define TT 512
#define BB 128
#define HH 512
#define NGROUP 8          // batch groups, 16 rows each
#define NSLICE 8          // col-slice blocks per group (4 waves x 16 cols each)
#define ALPHA 0.1f
#define NOISE_S 0.02f

typedef __attribute__((ext_vector_type(8))) short short8;
typedef __attribute__((ext_vector_type(8))) _Float16 half8;
typedef __attribute__((ext_vector_type(4))) float f32x4;

// ---- workspace layout (bytes) ----
#define WPACK_CH 132096                       // 16B chunks of packed weights
#define PUB1_B (WPACK_CH * 16)                // tanh1 pub: [NGROUP][8192] u32 words
#define PUB2_B (PUB1_B + NGROUP * 32768)      // tanh2 pub: [NGROUP][8192] u32 words
// pub word = (step_tag << 16) | fp16_bits ; word idx = kt*512 + srow*8 + j
// (identical index space as the LDS A-chunk tiles)

__device__ __forceinline__ unsigned short f2h(float f) {
  return __builtin_bit_cast(unsigned short, (_Float16)f);  // RNE
}

__device__ __forceinline__ float fast_tanh(float x) {
  float e = __builtin_amdgcn_exp2f(x * 2.8853900817779268f);
  return 1.0f - 2.0f * __builtin_amdgcn_rcpf(e + 1.0f);
}

__device__ __forceinline__ f32x4 mfma16(short8 a, short8 b, f32x4 c) {
  return __builtin_amdgcn_mfma_f32_16x16x32_f16(
      __builtin_bit_cast(half8, a), __builtin_bit_cast(half8, b), c, 0, 0, 0);
}

// ---------------------------------------------------------------------------
// Pack fp32 weights into fp16 MFMA B-fragment chunk order.
// chunk(kt, nt, lane)[i] = W[kt*32 + (lane>>4)*8 + i][nt*16 + (lane&15)]
//   WA = [wrec11; wrec12] (K=1024)  chunks [0, 65536)
//   WB = [wrec21; wrec22] (K=1024)  chunks [65536, 131072)
//   WO = wo padded to N=16 (K=512)  chunks [131072, 132096)
// ---------------------------------------------------------------------------
__global__ void pack_weights(const float* __restrict__ w11, const float* __restrict__ w12,
                             const float* __restrict__ w21, const float* __restrict__ w22,
                             const float* __restrict__ wo, unsigned short* __restrict__ dst) {
  int idx = blockIdx.x * 256 + threadIdx.x;
  if (idx < 131072) {
    int which = idx >> 16;
    int c0 = idx & 65535;
    int kt = c0 >> 11, rem = c0 & 2047;
    int nt = rem >> 6, lane = rem & 63;
    const float* wlo = which ? w21 : w11;   // k < 512  (multiplies tanh(h1))
    const float* whi = which ? w22 : w12;   // k >= 512 (multiplies tanh(h2))
    unsigned short* p = dst + (size_t)idx * 8;
    int n = nt * 16 + (lane & 15);
    int kb = kt * 32 + ((lane >> 4) & 3) * 8;
#pragma unroll
    for (int i = 0; i < 8; ++i) {
      int k = kb + i;
      float v = (k < HH) ? wlo[k * HH + n] : whi[(k - HH) * HH + n];
      p[i] = f2h(v);
    }
  } else if (idx < 132096) {
    int c0 = idx - 131072;
    int kt = c0 >> 6, lane = c0 & 63;
    unsigned short* p = dst + (size_t)131072 * 8 + (size_t)c0 * 8;
    int n = lane & 15;
    int kb = kt * 32 + ((lane >> 4) & 3) * 8;
#pragma unroll
    for (int i = 0; i < 8; ++i) {
      float v = (n < 3) ? wo[(kb + i) * 3 + n] : 0.0f;
      p[i] = f2h(v);
    }
  }
}

// zero pub1+pub2 each launch (tag 0 == initial state h=0, graph-replay safe)
__global__ void zero_ws(int* __restrict__ p, int n) {
  for (int i = blockIdx.x * 256 + threadIdx.x; i < n; i += gridDim.x * 256)
    p[i] = 0;
}

// ---------------------------------------------------------------------------
// Sliced persistent RNN; tag-in-data agent-scope sync (proven r7 transport)
// with COALESCED PUBLISH and OWN-CHUNK SKIP.
// Grid: 64 blocks = NSLICE(8) x NGROUP(8); 4 waves x 16 cols each.
// Epilogues write tanh values directly into the block's own LDS chunks, then
// (after a barrier) each thread publishes 4 contiguous words of the block's
// own 4KB pub region with two u64 agent stores (wave-coalesced lines, 4x
// fewer store transactions at the coherence point than scattered dwords).
// Staging polls only the 14 non-own chunks; own data never round-trips.
// Phase A (t): W11xT1 -> poll/stage pub2(tag>=t) -> barrier -> W12xT2
//   (+rotated out[t-1]) -> h1 update -> LDS write -> barrier -> publish pub1.
// Phase B: W22xT2 -> poll/stage pub1(tag>=t+1) -> barrier -> W21xT1' ->
//   h2 update -> LDS write -> barrier -> publish pub2.
// WAR-safe (unchanged): a block reaches its next pub overwrite only after
// polling the full peer set of the prior phase, which peers publish only
// after staging this pub -- tags never advance past a pending reader.
// ---------------------------------------------------------------------------
__global__ __launch_bounds__(256, 1)
void rnn_main(const float* __restrict__ x, const float* __restrict__ wi_stim,
              const float* __restrict__ wi_ctx, const float* __restrict__ noise1,
              const float* __restrict__ noise2, char* __restrict__ ws,
              float* __restrict__ out) {
  __shared__ __align__(16) unsigned short T1buf[16 * 512];  // tanh(h1) A-chunks
  __shared__ __align__(16) unsigned short T2buf[16 * 512];  // tanh(h2) A-chunks
  __shared__ __align__(16) unsigned short WOlds[16 * 512];  // wo B-chunks
  __shared__ float xstage[2][16][5];

  const int tid = threadIdx.x;
  const int w = tid >> 6, lane = tid & 63;
  const int c16 = lane & 15, kh = lane >> 4;
  const int g = blockIdx.x & (NGROUP - 1);
  const int slice = blockIdx.x >> 3;
  const int nt = slice * 4 + w;          // n-tile 0..31
  const int n0 = nt * 16;
  const int b0 = g * 16;
  const int lrow0 = kh * 4;

  const short8* __restrict__ WC = (const short8*)ws;
  unsigned* __restrict__ pub1 = (unsigned*)(ws + PUB1_B) + g * 8192;
  unsigned* __restrict__ pub2 = (unsigned*)(ws + PUB2_B) + g * 8192;

  // ---- init LDS ----
  short8 z = {0, 0, 0, 0, 0, 0, 0, 0};
  for (int i = tid; i < 1024; i += 256) {
    ((short8*)T1buf)[i] = z;             // tanh(0) = 0
    ((short8*)T2buf)[i] = z;
  }
#pragma unroll
  for (int c = 0; c < 4; ++c) {          // wo fragments to LDS (all blocks)
    int kt = w * 4 + c;
    short8 v = WC[131072 + kt * 64 + lane];
    *(short8*)&WOlds[kt * 512 + lane * 8] = v;
  }
  if (tid < 80) {
    int b = tid / 5, c = tid % 5;
    xstage[0][b][c] = x[((size_t)(b0 + b) * TT + 0) * 5 + c];
  }

  float wis[3], wic[2];
#pragma unroll
  for (int c = 0; c < 3; ++c) wis[c] = wi_stim[c * HH + n0 + c16];
#pragma unroll
  for (int c = 0; c < 2; ++c) wic[c] = wi_ctx[c * HH + n0 + c16];

  float h1[4] = {0, 0, 0, 0}, h2[4] = {0, 0, 0, 0};

  // epilogue LDS address: value (row=lrow0+r, col=n0+c16) -> chunk entry
  const int kt_p = nt >> 1;
  const int hi = (((nt & 1) * 16) + c16) >> 3;
  const int ci = c16 & 7;
  const int lslot = kt_p * 512 + (lrow0 + hi * 16) * 8 + ci;  // +r*8

  // own pub region: words [1024*slice, 1024*slice+1024)
  const int pbase = slice * 1024 + tid * 4;

  const short8* __restrict__ WAp = WC + nt * 64 + lane;           // +kt*2048
  const short8* __restrict__ WBp = WC + 65536 + nt * 64 + lane;

  // read 4 own LDS entries, tag, publish as two coalesced u64 agent stores
  auto publish_own = [&](const unsigned short* Tbuf, unsigned* pubw, unsigned tagN) {
    unsigned long long lv = *(const unsigned long long*)&Tbuf[pbase];
    unsigned w0 = tagN | (unsigned)(lv & 0xffffull);
    unsigned w1 = tagN | (unsigned)((lv >> 16) & 0xffffull);
    unsigned w2 = tagN | (unsigned)((lv >> 32) & 0xffffull);
    unsigned w3 = tagN | (unsigned)((lv >> 48) & 0xffffull);
    unsigned long long p0 = (unsigned long long)w0 | ((unsigned long long)w1 << 32);
    unsigned long long p1 = (unsigned long long)w2 | ((unsigned long long)w3 << 32);
    unsigned long long* dst = (unsigned long long*)&pubw[pbase];
    __hip_atomic_store(&dst[0], p0, __ATOMIC_RELAXED, __HIP_MEMORY_SCOPE_AGENT);
    __hip_atomic_store(&dst[1], p1, __ATOMIC_RELAXED, __HIP_MEMORY_SCOPE_AGENT);
  };

  // poll own quarter (skipping own block's chunks) until tags >= exp; unpack
  auto stage_poll = [&](const unsigned* pubw, unsigned short* Tbuf, unsigned exp) {
    unsigned long long v[4][4];
    for (;;) {
      bool ok = true;
#pragma unroll
      for (int c = 0; c < 4; ++c) {
        int kt = w * 4 + c;
        if ((kt >> 1) == slice) continue;      // own chunk: LDS already fresh
        const unsigned long long* src =
            (const unsigned long long*)(pubw + (kt << 9)) + lane * 4;
#pragma unroll
        for (int j = 0; j < 4; ++j) {
          v[c][j] = __hip_atomic_load(&src[j], __ATOMIC_RELAXED,
                                      __HIP_MEMORY_SCOPE_AGENT);
          ok &= (((unsigned)(v[c][j] >> 16) & 0xffffu) >= exp);
          ok &= ((unsigned)(v[c][j] >> 48) >= exp);
        }
      }
      if (ok) break;
    }
    __builtin_amdgcn_sched_barrier(0);
    asm volatile("" ::: "memory");
#pragma unroll
    for (int c = 0; c < 4; ++c) {
      int kt = w * 4 + c;
      if ((kt >> 1) == slice) continue;
      unsigned long long u0 = (v[c][0] & 0xffffull)
                            | (((v[c][0] >> 32) & 0xffffull) << 16)
                            | ((v[c][1] & 0xffffull) << 32)
                            | (((v[c][1] >> 32) & 0xffffull) << 48);
      unsigned long long u1 = (v[c][2] & 0xffffull)
                            | (((v[c][2] >> 32) & 0xffffull) << 16)
                            | ((v[c][3] & 0xffffull) << 32)
                            | (((v[c][3] >> 32) & 0xffffull) << 48);
      *(unsigned long long*)&Tbuf[kt * 512 + lane * 8] = u0;
      *(unsigned long long*)&Tbuf[kt * 512 + lane * 8 + 4] = u1;
    }
  };

  __syncthreads();

  for (int t = 0; t < TT; ++t) {
    const int buf = t & 1;
    const unsigned tagN = (unsigned)(t + 1) << 16;

    // per-step inputs (early issue; consumed in epilogues)
    float n1v[4], n2v[4];
#pragma unroll
    for (int r = 0; r < 4; ++r) {
      size_t rowoff = ((size_t)t * BB + b0 + lrow0 + r) * HH + n0 + c16;
      n1v[r] = noise1[rowoff];
      n2v[r] = noise2[rowoff];
    }

    // ================= phase A =================
    f32x4 aA = {0, 0, 0, 0}, aB = {0, 0, 0, 0};
#pragma unroll
    for (int kt = 0; kt < 16; ++kt) {    // W11 x T1 (local, stable)
      short8 a1 = *(const short8*)&T1buf[kt * 512 + lane * 8];
      aA = mfma16(a1, WAp[kt * 2048], aA);
    }
    stage_poll(pub2, T2buf, (unsigned)t);   // tanh(h2[t]) from peers
    __syncthreads();
#pragma unroll
    for (int kt = 0; kt < 16; ++kt) {    // W12 x T2
      short8 a2 = *(const short8*)&T2buf[kt * 512 + lane * 8];
      aB = mfma16(a2, WAp[(16 + kt) * 2048], aB);
    }

    // rotated output for step t-1: out[t-1] = tanh(h2[t]) @ wo
    if (t > 0 && slice == ((t - 1) & 7) && w == 0) {
      f32x4 ao = {0, 0, 0, 0};
#pragma unroll
      for (int kt = 0; kt < 16; ++kt) {
        short8 a2 = *(const short8*)&T2buf[kt * 512 + lane * 8];
        short8 bo = *(const short8*)&WOlds[kt * 512 + lane * 8];
        ao = mfma16(a2, bo, ao);
      }
      if (c16 < 3) {
#pragma unroll
        for (int r = 0; r < 4; ++r)
          out[((size_t)(b0 + lrow0 + r) * TT + (t - 1)) * 3 + c16] = ao[r];
      }
    }

#pragma unroll
    for (int r = 0; r < 4; ++r) {        // h1 update -> LDS (own chunks)
      float pre = aA[r] + aB[r]
                + wis[0] * xstage[buf][lrow0 + r][0]
                + wis[1] * xstage[buf][lrow0 + r][1]
                + wis[2] * xstage[buf][lrow0 + r][2]
                + NOISE_S * n1v[r];
      float h = (1.0f - ALPHA) * h1[r] + ALPHA * pre;
      h1[r] = h;
      T1buf[lslot + r * 8] = f2h(fast_tanh(h));
    }
    __syncthreads();                     // own T1 chunks complete in LDS
    publish_own(T1buf, pub1, tagN);

    // ================= phase B =================
    f32x4 bA = {0, 0, 0, 0}, bB = {0, 0, 0, 0};
#pragma unroll
    for (int kt = 0; kt < 16; ++kt) {    // W22 x T2 (stable across sync)
      short8 a2 = *(const short8*)&T2buf[kt * 512 + lane * 8];
      bB = mfma16(a2, WBp[(16 + kt) * 2048], bB);
    }
    stage_poll(pub1, T1buf, (unsigned)(t + 1));  // fresh tanh(h1') from peers
    if (t + 1 < TT && tid < 80) {
      int b = tid / 5, c = tid % 5;
      xstage[buf ^ 1][b][c] = x[((size_t)(b0 + b) * TT + (t + 1)) * 5 + c];
    }
    __syncthreads();
#pragma unroll
    for (int kt = 0; kt < 16; ++kt) {    // W21 x fresh tanh(h1')
      short8 a1 = *(const short8*)&T1buf[kt * 512 + lane * 8];
      bA = mfma16(a1, WBp[kt * 2048], bA);
    }
#pragma unroll
    for (int r = 0; r < 4; ++r) {        // h2 update -> LDS (own chunks)
      float pre = bA[r] + bB[r]
                + wic[0] * xstage[buf][lrow0 + r][3]
                + wic[1] * xstage[buf][lrow0 + r][4]
                + NOISE_S * n2v[r];
      float h = (1.0f - ALPHA) * h2[r] + ALPHA * pre;
      h2[r] = h;
      T2buf[lslot + r * 8] = f2h(fast_tanh(h));
    }
    __syncthreads();                     // own T2 chunks complete in LDS
    publish_own(T2buf, pub2, tagN);
  }

  // ---- final output: out[TT-1] = tanh(h2[TT]) @ wo ----
  if (slice == ((TT - 1) & 7)) {
    stage_poll(pub2, T2buf, (unsigned)TT);
    __syncthreads();
    if (w == 0) {
      f32x4 ao = {0, 0, 0, 0};
#pragma unroll
      for (int kt = 0; kt < 16; ++kt) {
        short8 a2 = *(const short8*)&T2buf[kt * 512 + lane * 8];
        short8 bo = *(const short8*)&WOlds[kt * 512 + lane * 8];
        ao = mfma16(a2, bo, ao);
      }
      if (c16 < 3) {
#pragma unroll
        for (int r = 0; r < 4; ++r)
          out[((size_t)(b0 + lrow0 + r) * TT + (TT - 1)) * 3 + c16] = ao[r];
      }
    }
  }
}

extern "C" void kernel_launch(void* const* d_in, const int* in_sizes, int n_in,
                              void* d_out, int out_size, void* d_ws, size_t ws_size,
                              hipStream_t stream) {
  const float* x       = (const float*)d_in[0];
  const float* wi_stim = (const float*)d_in[1];
  const float* w11     = (const float*)d_in[2];
  const float* wi_ctx  = (const float*)d_in[3];
  const float* w22     = (const float*)d_in[4];
  const float* w12     = (const float*)d_in[5];
  const float* w21     = (const float*)d_in[6];
  const float* wo      = (const float*)d_in[7];
  const float* n1      = (const float*)d_in[8];
  const float* n2      = (const float*)d_in[9];
  char* ws = (char*)d_ws;                  // needs ~2.7 MB

  int nz = (NGROUP * 32768 * 2) / 4;       // pub1+pub2 words
  zero_ws<<<64, 256, 0, stream>>>((int*)(ws + PUB1_B), nz);
  pack_weights<<<516, 256, 0, stream>>>(w11, w12, w21, w22, wo,
                                        (unsigned short*)ws);
  rnn_main<<<NSLICE * NGROUP, 256, 0, stream>>>(x, wi_stim, wi_ctx, n1, n2, ws,
                                                (float*)d_out);
}

// Round 17
// 4211.852 us; speedup vs baseline: 2.5410x; 1.0209x over previous
//
#include <hip/hip_runtime.h>
#include <hip/hip_bf16.h>

#define TT 512
#define BB 128
#define HH 512
#define NGROUP 8          // batch groups, 16 rows each
#define NSLICE 8          // col-slice blocks per group (4 waves x 16 cols each)
#define ALPHA 0.1f
#define NOISE_S 0.02f

typedef __attribute__((ext_vector_type(8))) short short8;
typedef __attribute__((ext_vector_type(8))) _Float16 half8;
typedef __attribute__((ext_vector_type(4))) float f32x4;

// ---- workspace layout (bytes) ----
#define WPACK_CH 132096                       // 16B chunks of packed weights
#define PUB1_B (WPACK_CH * 16)                // tanh1 pub: [NGROUP][8192] u32 words
#define PUB2_B (PUB1_B + NGROUP * 32768)      // tanh2 pub: [NGROUP][8192] u32 words
// pub word = (step_tag << 16) | fp16_bits ; word idx = kt*512 + srow*8 + j

__device__ __forceinline__ unsigned short f2h(float f) {
  return __builtin_bit_cast(unsigned short, (_Float16)f);  // RNE
}

__device__ __forceinline__ float fast_tanh(float x) {
  float e = __builtin_amdgcn_exp2f(x * 2.8853900817779268f);
  return 1.0f - 2.0f * __builtin_amdgcn_rcpf(e + 1.0f);
}

__device__ __forceinline__ f32x4 mfma16(short8 a, short8 b, f32x4 c) {
  return __builtin_amdgcn_mfma_f32_16x16x32_f16(
      __builtin_bit_cast(half8, a), __builtin_bit_cast(half8, b), c, 0, 0, 0);
}

// ---------------------------------------------------------------------------
// Pack fp32 weights into fp16 MFMA B-fragment chunk order.
// chunk(kt, nt, lane)[i] = W[kt*32 + (lane>>4)*8 + i][nt*16 + (lane&15)]
//   WA = [wrec11; wrec12] (K=1024)  chunks [0, 65536)
//   WB = [wrec21; wrec22] (K=1024)  chunks [65536, 131072)
//   WO = wo padded to N=16 (K=512)  chunks [131072, 132096)
// ---------------------------------------------------------------------------
__global__ void pack_weights(const float* __restrict__ w11, const float* __restrict__ w12,
                             const float* __restrict__ w21, const float* __restrict__ w22,
                             const float* __restrict__ wo, unsigned short* __restrict__ dst) {
  int idx = blockIdx.x * 256 + threadIdx.x;
  if (idx < 131072) {
    int which = idx >> 16;
    int c0 = idx & 65535;
    int kt = c0 >> 11, rem = c0 & 2047;
    int nt = rem >> 6, lane = rem & 63;
    const float* wlo = which ? w21 : w11;   // k < 512  (multiplies tanh(h1))
    const float* whi = which ? w22 : w12;   // k >= 512 (multiplies tanh(h2))
    unsigned short* p = dst + (size_t)idx * 8;
    int n = nt * 16 + (lane & 15);
    int kb = kt * 32 + ((lane >> 4) & 3) * 8;
#pragma unroll
    for (int i = 0; i < 8; ++i) {
      int k = kb + i;
      float v = (k < HH) ? wlo[k * HH + n] : whi[(k - HH) * HH + n];
      p[i] = f2h(v);
    }
  } else if (idx < 132096) {
    int c0 = idx - 131072;
    int kt = c0 >> 6, lane = c0 & 63;
    unsigned short* p = dst + (size_t)131072 * 8 + (size_t)c0 * 8;
    int n = lane & 15;
    int kb = kt * 32 + ((lane >> 4) & 3) * 8;
#pragma unroll
    for (int i = 0; i < 8; ++i) {
      float v = (n < 3) ? wo[(kb + i) * 3 + n] : 0.0f;
      p[i] = f2h(v);
    }
  }
}

// zero pub1+pub2 each launch (tag 0 == initial state h=0, graph-replay safe)
__global__ void zero_ws(int* __restrict__ p, int n) {
  for (int i = blockIdx.x * 256 + threadIdx.x; i < n; i += gridDim.x * 256)
    p[i] = 0;
}

// ---------------------------------------------------------------------------
// Sliced persistent RNN; tag-in-data agent-scope sync (proven r7 transport)
// + PER-PHASE REGISTER PREFETCH of the post-poll weight half.
// Grid: 64 blocks = NSLICE(8) x NGROUP(8); 4 waves x 16 cols each.
// Phase A (t): prefetch W12-half -> regs | stream W11 x T1 MFMAs |
//   poll/stage pub2(tag>=t) -> barrier -> W12 x T2 from REGS (no L2 wait)
//   (+rotated out[t-1]) -> h1 update -> publish pub1 tag t+1 (scattered dw).
// Phase B: prefetch W21-half -> regs | stream W22 x T2 | poll/stage
//   pub1(tag>=t+1) -> barrier -> W21 x T1' from REGS -> h2 update ->
//   publish pub2 tag t+1.
// WAR-safe (unchanged): tags never advance past a pending reader.
// ---------------------------------------------------------------------------
__global__ __launch_bounds__(256, 1)
void rnn_main(const float* __restrict__ x, const float* __restrict__ wi_stim,
              const float* __restrict__ wi_ctx, const float* __restrict__ noise1,
              const float* __restrict__ noise2, char* __restrict__ ws,
              float* __restrict__ out) {
  __shared__ __align__(16) unsigned short T1buf[16 * 512];  // tanh(h1) A-chunks
  __shared__ __align__(16) unsigned short T2buf[16 * 512];  // tanh(h2) A-chunks
  __shared__ __align__(16) unsigned short WOlds[16 * 512];  // wo B-chunks
  __shared__ float xstage[2][16][5];

  const int tid = threadIdx.x;
  const int w = tid >> 6, lane = tid & 63;
  const int c16 = lane & 15, kh = lane >> 4;
  const int g = blockIdx.x & (NGROUP - 1);
  const int slice = blockIdx.x >> 3;
  const int nt = slice * 4 + w;          // n-tile 0..31
  const int n0 = nt * 16;
  const int b0 = g * 16;
  const int lrow0 = kh * 4;

  const short8* __restrict__ WC = (const short8*)ws;
  unsigned* __restrict__ pub1 = (unsigned*)(ws + PUB1_B) + g * 8192;
  unsigned* __restrict__ pub2 = (unsigned*)(ws + PUB2_B) + g * 8192;

  // ---- init LDS ----
  short8 z = {0, 0, 0, 0, 0, 0, 0, 0};
  for (int i = tid; i < 1024; i += 256) {
    ((short8*)T1buf)[i] = z;             // tanh(0) = 0
    ((short8*)T2buf)[i] = z;
  }
#pragma unroll
  for (int c = 0; c < 4; ++c) {          // wo fragments to LDS (all blocks)
    int kt = w * 4 + c;
    short8 v = WC[131072 + kt * 64 + lane];
    *(short8*)&WOlds[kt * 512 + lane * 8] = v;
  }
  if (tid < 80) {
    int b = tid / 5, c = tid % 5;
    xstage[0][b][c] = x[((size_t)(b0 + b) * TT + 0) * 5 + c];
  }

  float wis[3], wic[2];
#pragma unroll
  for (int c = 0; c < 3; ++c) wis[c] = wi_stim[c * HH + n0 + c16];
#pragma unroll
  for (int c = 0; c < 2; ++c) wic[c] = wi_ctx[c * HH + n0 + c16];

  float h1[4] = {0, 0, 0, 0}, h2[4] = {0, 0, 0, 0};

  // publish address components: value (row=lrow0+r, col=n0+c16) -> word slot
  const int kt_p = nt >> 1;
  const int hi = (((nt & 1) * 16) + c16) >> 3;
  const int ci = c16 & 7;
  const int pslot = kt_p * 512 + (lrow0 + hi * 16) * 8 + ci;  // +r*8

  const short8* __restrict__ WAp = WC + nt * 64 + lane;           // +kt*2048
  const short8* __restrict__ WBp = WC + 65536 + nt * 64 + lane;

  // poll own quarter until all tags >= exp, then unpack into LDS (r7-proven)
  auto stage_poll = [&](const unsigned* pubw, unsigned short* Tbuf, unsigned exp) {
    unsigned long long v[4][4];
    for (;;) {
      bool ok = true;
#pragma unroll
      for (int c = 0; c < 4; ++c) {
        const unsigned long long* src =
            (const unsigned long long*)(pubw + ((w * 4 + c) << 9)) + lane * 4;
#pragma unroll
        for (int j = 0; j < 4; ++j) {
          v[c][j] = __hip_atomic_load(&src[j], __ATOMIC_RELAXED,
                                      __HIP_MEMORY_SCOPE_AGENT);
          ok &= (((unsigned)(v[c][j] >> 16) & 0xffffu) >= exp);
          ok &= ((unsigned)(v[c][j] >> 48) >= exp);
        }
      }
      if (ok) break;
    }
    __builtin_amdgcn_sched_barrier(0);
    asm volatile("" ::: "memory");
#pragma unroll
    for (int c = 0; c < 4; ++c) {
      unsigned long long u0 = (v[c][0] & 0xffffull)
                            | (((v[c][0] >> 32) & 0xffffull) << 16)
                            | ((v[c][1] & 0xffffull) << 32)
                            | (((v[c][1] >> 32) & 0xffffull) << 48);
      unsigned long long u1 = (v[c][2] & 0xffffull)
                            | (((v[c][2] >> 32) & 0xffffull) << 16)
                            | ((v[c][3] & 0xffffull) << 32)
                            | (((v[c][3] >> 32) & 0xffffull) << 48);
      *(unsigned long long*)&Tbuf[(w * 4 + c) * 512 + lane * 8] = u0;
      *(unsigned long long*)&Tbuf[(w * 4 + c) * 512 + lane * 8 + 4] = u1;
    }
  };

  __syncthreads();

  for (int t = 0; t < TT; ++t) {
    const int buf = t & 1;
    const unsigned tagN = (unsigned)(t + 1) << 16;

    // per-step inputs (early issue; consumed in epilogues)
    float n1v[4], n2v[4];
#pragma unroll
    for (int r = 0; r < 4; ++r) {
      size_t rowoff = ((size_t)t * BB + b0 + lrow0 + r) * HH + n0 + c16;
      n1v[r] = noise1[rowoff];
      n2v[r] = noise2[rowoff];
    }

    // ================= phase A =================
    // prefetch the POST-poll weight half (W12) into registers: its L2
    // latency overlaps the W11 cluster + peers' publish propagation.
    short8 wa2[16];
#pragma unroll
    for (int kt = 0; kt < 16; ++kt) wa2[kt] = WAp[(16 + kt) * 2048];

    f32x4 aA = {0, 0, 0, 0}, aB = {0, 0, 0, 0};
#pragma unroll
    for (int kt = 0; kt < 16; ++kt) {    // W11 x T1 (streamed, pre-poll)
      short8 a1 = *(const short8*)&T1buf[kt * 512 + lane * 8];
      aA = mfma16(a1, WAp[kt * 2048], aA);
    }
    stage_poll(pub2, T2buf, (unsigned)t);   // tanh(h2[t])
    __syncthreads();
#pragma unroll
    for (int kt = 0; kt < 16; ++kt) {    // W12 x T2 from REGISTERS
      short8 a2 = *(const short8*)&T2buf[kt * 512 + lane * 8];
      aB = mfma16(a2, wa2[kt], aB);
    }

    // rotated output for step t-1: out[t-1] = tanh(h2[t]) @ wo
    if (t > 0 && slice == ((t - 1) & 7) && w == 0) {
      f32x4 ao = {0, 0, 0, 0};
#pragma unroll
      for (int kt = 0; kt < 16; ++kt) {
        short8 a2 = *(const short8*)&T2buf[kt * 512 + lane * 8];
        short8 bo = *(const short8*)&WOlds[kt * 512 + lane * 8];
        ao = mfma16(a2, bo, ao);
      }
      if (c16 < 3) {
#pragma unroll
        for (int r = 0; r < 4; ++r)
          out[((size_t)(b0 + lrow0 + r) * TT + (t - 1)) * 3 + c16] = ao[r];
      }
    }

    unsigned short tp[4];
#pragma unroll
    for (int r = 0; r < 4; ++r) {
      float pre = aA[r] + aB[r]
                + wis[0] * xstage[buf][lrow0 + r][0]
                + wis[1] * xstage[buf][lrow0 + r][1]
                + wis[2] * xstage[buf][lrow0 + r][2]
                + NOISE_S * n1v[r];
      float h = (1.0f - ALPHA) * h1[r] + ALPHA * pre;
      h1[r] = h;
      tp[r] = f2h(fast_tanh(h));
    }
#pragma unroll
    for (int r = 0; r < 4; ++r)
      __hip_atomic_store(&pub1[pslot + r * 8], tagN | tp[r],
                         __ATOMIC_RELAXED, __HIP_MEMORY_SCOPE_AGENT);

    // ================= phase B =================
    // prefetch the POST-poll weight half (W21) into registers.
    short8 wb1[16];
#pragma unroll
    for (int kt = 0; kt < 16; ++kt) wb1[kt] = WBp[kt * 2048];

    f32x4 bA = {0, 0, 0, 0}, bB = {0, 0, 0, 0};
#pragma unroll
    for (int kt = 0; kt < 16; ++kt) {    // W22 x T2 (streamed, pre-poll)
      short8 a2 = *(const short8*)&T2buf[kt * 512 + lane * 8];
      bB = mfma16(a2, WBp[(16 + kt) * 2048], bB);
    }
    stage_poll(pub1, T1buf, (unsigned)(t + 1));  // fresh tanh(h1')
    if (t + 1 < TT && tid < 80) {
      int b = tid / 5, c = tid % 5;
      xstage[buf ^ 1][b][c] = x[((size_t)(b0 + b) * TT + (t + 1)) * 5 + c];
    }
    __syncthreads();
#pragma unroll
    for (int kt = 0; kt < 16; ++kt) {    // W21 x fresh T1' from REGISTERS
      short8 a1 = *(const short8*)&T1buf[kt * 512 + lane * 8];
      bA = mfma16(a1, wb1[kt], bA);
    }
#pragma unroll
    for (int r = 0; r < 4; ++r) {
      float pre = bA[r] + bB[r]
                + wic[0] * xstage[buf][lrow0 + r][3]
                + wic[1] * xstage[buf][lrow0 + r][4]
                + NOISE_S * n2v[r];
      float h = (1.0f - ALPHA) * h2[r] + ALPHA * pre;
      h2[r] = h;
      tp[r] = f2h(fast_tanh(h));
    }
#pragma unroll
    for (int r = 0; r < 4; ++r)
      __hip_atomic_store(&pub2[pslot + r * 8], tagN | tp[r],
                         __ATOMIC_RELAXED, __HIP_MEMORY_SCOPE_AGENT);
  }

  // ---- final output: out[TT-1] = tanh(h2[TT]) @ wo ----
  if (slice == ((TT - 1) & 7)) {
    stage_poll(pub2, T2buf, (unsigned)TT);
    __syncthreads();
    if (w == 0) {
      f32x4 ao = {0, 0, 0, 0};
#pragma unroll
      for (int kt = 0; kt < 16; ++kt) {
        short8 a2 = *(const short8*)&T2buf[kt * 512 + lane * 8];
        short8 bo = *(const short8*)&WOlds[kt * 512 + lane * 8];
        ao = mfma16(a2, bo, ao);
      }
      if (c16 < 3) {
#pragma unroll
        for (int r = 0; r < 4; ++r)
          out[((size_t)(b0 + lrow0 + r) * TT + (TT - 1)) * 3 + c16] = ao[r];
      }
    }
  }
}

extern "C" void kernel_launch(void* const* d_in, const int* in_sizes, int n_in,
                              void* d_out, int out_size, void* d_ws, size_t ws_size,
                              hipStream_t stream) {
  const float* x       = (const float*)d_in[0];
  const float* wi_stim = (const float*)d_in[1];
  const float* w11     = (const float*)d_in[2];
  const float* wi_ctx  = (const float*)d_in[3];
  const float* w22     = (const float*)d_in[4];
  const float* w12     = (const float*)d_in[5];
  const float* w21     = (const float*)d_in[6];
  const float* wo      = (const float*)d_in[7];
  const float* n1      = (const float*)d_in[8];
  const float* n2      = (const float*)d_in[9];
  char* ws = (char*)d_ws;                  // needs ~2.7 MB

  int nz = (NGROUP * 32768 * 2) / 4;       // pub1+pub2 words
  zero_ws<<<64, 256, 0, stream>>>((int*)(ws + PUB1_B), nz);
  pack_weights<<<516, 256, 0, stream>>>(w11, w12, w21, w22, wo,
                                        (unsigned short*)ws);
  rnn_main<<<NSLICE * NGROUP, 256, 0, stream>>>(x, wi_stim, wi_ctx, n1, n2, ws,
                                                (float*)d_out);
}

// Round 18
// 3799.997 us; speedup vs baseline: 2.8164x; 1.1084x over previous
//
#include <hip/hip_runtime.h>
#include <hip/hip_bf16.h>

#define TT 512
#define BB 128
#define HH 512
#define NGROUP 8          // batch groups, 16 rows each
#define NSLICE 8          // col-slice blocks per group (4 waves x 16 cols each)
#define ALPHA 0.1f
#define NOISE_S 0.02f

typedef __attribute__((ext_vector_type(8))) short short8;
typedef __attribute__((ext_vector_type(8))) _Float16 half8;
typedef __attribute__((ext_vector_type(4))) float f32x4;

// ---- workspace layout (bytes) ----
#define WPACK_CH 132096                       // 16B chunks of packed weights
#define PUB1_B (WPACK_CH * 16)                // tanh1 pub: [NGROUP][8192] u32 words
#define PUB2_B (PUB1_B + NGROUP * 32768)      // tanh2 pub: [NGROUP][8192] u32 words
// word = (step_tag << 16) | fp16_bits ; word idx = kt*512 + srow*8 + j

__device__ __forceinline__ unsigned short f2h(float f) {
  return __builtin_bit_cast(unsigned short, (_Float16)f);  // RNE
}

__device__ __forceinline__ float fast_tanh(float x) {
  float e = __builtin_amdgcn_exp2f(x * 2.8853900817779268f);
  return 1.0f - 2.0f * __builtin_amdgcn_rcpf(e + 1.0f);
}

__device__ __forceinline__ f32x4 mfma16(short8 a, short8 b, f32x4 c) {
  return __builtin_amdgcn_mfma_f32_16x16x32_f16(
      __builtin_bit_cast(half8, a), __builtin_bit_cast(half8, b), c, 0, 0, 0);
}

// ---------------------------------------------------------------------------
// Pack fp32 weights into fp16 MFMA B-fragment chunk order.
// chunk(kt, nt, lane)[i] = W[kt*32 + (lane>>4)*8 + i][nt*16 + (lane&15)]
//   WA = [wrec11; wrec12] (K=1024)  chunks [0, 65536)
//   WB = [wrec21; wrec22] (K=1024)  chunks [65536, 131072)
//   WO = wo padded to N=16 (K=512)  chunks [131072, 132096)
// ---------------------------------------------------------------------------
__global__ void pack_weights(const float* __restrict__ w11, const float* __restrict__ w12,
                             const float* __restrict__ w21, const float* __restrict__ w22,
                             const float* __restrict__ wo, unsigned short* __restrict__ dst) {
  int idx = blockIdx.x * 256 + threadIdx.x;
  if (idx < 131072) {
    int which = idx >> 16;
    int c0 = idx & 65535;
    int kt = c0 >> 11, rem = c0 & 2047;
    int nt = rem >> 6, lane = rem & 63;
    const float* wlo = which ? w21 : w11;   // k < 512  (multiplies tanh(h1))
    const float* whi = which ? w22 : w12;   // k >= 512 (multiplies tanh(h2))
    unsigned short* p = dst + (size_t)idx * 8;
    int n = nt * 16 + (lane & 15);
    int kb = kt * 32 + ((lane >> 4) & 3) * 8;
#pragma unroll
    for (int i = 0; i < 8; ++i) {
      int k = kb + i;
      float v = (k < HH) ? wlo[k * HH + n] : whi[(k - HH) * HH + n];
      p[i] = f2h(v);
    }
  } else if (idx < 132096) {
    int c0 = idx - 131072;
    int kt = c0 >> 6, lane = c0 & 63;
    unsigned short* p = dst + (size_t)131072 * 8 + (size_t)c0 * 8;
    int n = lane & 15;
    int kb = kt * 32 + ((lane >> 4) & 3) * 8;
#pragma unroll
    for (int i = 0; i < 8; ++i) {
      float v = (n < 3) ? wo[(kb + i) * 3 + n] : 0.0f;
      p[i] = f2h(v);
    }
  }
}

// zero pub1+pub2 each launch (tag 0 == initial state h=0, graph-replay safe)
__global__ void zero_ws(int* __restrict__ p, int n) {
  for (int i = blockIdx.x * 256 + threadIdx.x; i < n; i += gridDim.x * 256)
    p[i] = 0;
}

// ---------------------------------------------------------------------------
// Sliced persistent RNN; tag-in-data sync (no flags, no fences), VGPR-resident
// weights. Grid: 64 blocks = NSLICE(8) x NGROUP(8).
// Phase A (step t): W11xT1 -> poll/stage pub2(tag>=t) -> barrier -> W12xT2
//   (+rotated out[t-1]) -> h1 update -> publish pub1 tag t+1.
// Phase B: W22xT2 -> poll/stage pub1(tag>=t+1) -> barrier -> W21xT1' ->
//   h2 update -> publish pub2 tag t+1.
// WAR-safe: a producer reaches its next pub overwrite only after staging the
// full peer pub of the prior phase, which peers publish only after staging
// this pub -- tags never advance past a pending reader.
// ---------------------------------------------------------------------------
__global__ __launch_bounds__(256, 1)
void rnn_main(const float* __restrict__ x, const float* __restrict__ wi_stim,
              const float* __restrict__ wi_ctx, const float* __restrict__ noise1,
              const float* __restrict__ noise2, char* __restrict__ ws,
              float* __restrict__ out) {
  __shared__ __align__(16) unsigned short T1buf[16 * 512];  // tanh(h1) A-chunks
  __shared__ __align__(16) unsigned short T2buf[16 * 512];  // tanh(h2) A-chunks
  __shared__ __align__(16) unsigned short WOlds[16 * 512];  // wo B-chunks
  __shared__ float xstage[2][16][5];

  const int tid = threadIdx.x;
  const int w = tid >> 6, lane = tid & 63;
  const int c16 = lane & 15, kh = lane >> 4;
  const int g = blockIdx.x & (NGROUP - 1);
  const int slice = blockIdx.x >> 3;
  const int nt = slice * 4 + w;          // n-tile 0..31
  const int n0 = nt * 16;
  const int b0 = g * 16;
  const int lrow0 = kh * 4;

  const short8* __restrict__ WC = (const short8*)ws;
  unsigned* __restrict__ pub1 = (unsigned*)(ws + PUB1_B) + g * 8192;
  unsigned* __restrict__ pub2 = (unsigned*)(ws + PUB2_B) + g * 8192;

  // ---- init LDS ----
  short8 z = {0, 0, 0, 0, 0, 0, 0, 0};
  for (int i = tid; i < 1024; i += 256) {
    ((short8*)T1buf)[i] = z;             // tanh(0) = 0
    ((short8*)T2buf)[i] = z;
  }
#pragma unroll
  for (int c = 0; c < 4; ++c) {          // wo fragments to LDS (all blocks)
    int kt = w * 4 + c;
    short8 v = WC[131072 + kt * 64 + lane];
    *(short8*)&WOlds[kt * 512 + lane * 8] = v;
  }
  if (tid < 80) {
    int b = tid / 5, c = tid % 5;
    xstage[0][b][c] = x[((size_t)(b0 + b) * TT + 0) * 5 + c];
  }

  // ---- weights to VGPRs, pinned resident for all 512 steps ----
  short8 wA[32], wB[32];
#pragma unroll
  for (int kt = 0; kt < 32; ++kt) {
    wA[kt] = WC[kt * 2048 + nt * 64 + lane];
    wB[kt] = WC[65536 + kt * 2048 + nt * 64 + lane];
  }
#pragma unroll
  for (int kt = 0; kt < 32; ++kt) {
    asm volatile("" : "+v"(wA[kt]));
    asm volatile("" : "+v"(wB[kt]));
  }

  float wis[3], wic[2];
#pragma unroll
  for (int c = 0; c < 3; ++c) wis[c] = wi_stim[c * HH + n0 + c16];
#pragma unroll
  for (int c = 0; c < 2; ++c) wic[c] = wi_ctx[c * HH + n0 + c16];

  float h1[4] = {0, 0, 0, 0}, h2[4] = {0, 0, 0, 0};

  // publish address components: value (row=lrow0+r, col=n0+c16) -> word slot
  const int kt_p = nt >> 1;
  const int hi = (((nt & 1) * 16) + c16) >> 3;
  const int ci = c16 & 7;
  const int pslot = kt_p * 512 + (lrow0 + hi * 16) * 8 + ci;  // +r*8

  // poll own quarter until all tags >= exp, then unpack into LDS
  auto stage_poll = [&](const unsigned* pubw, unsigned short* Tbuf, unsigned exp) {
    unsigned long long v[4][4];
    for (;;) {
      bool ok = true;
#pragma unroll
      for (int c = 0; c < 4; ++c) {
        const unsigned long long* src =
            (const unsigned long long*)(pubw + ((w * 4 + c) << 9)) + lane * 4;
#pragma unroll
        for (int j = 0; j < 4; ++j) {
          v[c][j] = __hip_atomic_load(&src[j], __ATOMIC_RELAXED,
                                      __HIP_MEMORY_SCOPE_AGENT);
          ok &= (((unsigned)(v[c][j] >> 16) & 0xffffu) >= exp);
          ok &= ((unsigned)(v[c][j] >> 48) >= exp);
        }
      }
      if (ok) break;
    }
    __builtin_amdgcn_sched_barrier(0);
    asm volatile("" ::: "memory");
#pragma unroll
    for (int c = 0; c < 4; ++c) {
      unsigned long long u0 = (v[c][0] & 0xffffull)
                            | (((v[c][0] >> 32) & 0xffffull) << 16)
                            | ((v[c][1] & 0xffffull) << 32)
                            | (((v[c][1] >> 32) & 0xffffull) << 48);
      unsigned long long u1 = (v[c][2] & 0xffffull)
                            | (((v[c][2] >> 32) & 0xffffull) << 16)
                            | ((v[c][3] & 0xffffull) << 32)
                            | (((v[c][3] >> 32) & 0xffffull) << 48);
      *(unsigned long long*)&Tbuf[(w * 4 + c) * 512 + lane * 8] = u0;
      *(unsigned long long*)&Tbuf[(w * 4 + c) * 512 + lane * 8 + 4] = u1;
    }
  };

  __syncthreads();

  for (int t = 0; t < TT; ++t) {
    const int buf = t & 1;
    const unsigned tagN = (unsigned)(t + 1) << 16;

    // per-step inputs (early issue; consumed in epilogues)
    float n1v[4], n2v[4];
#pragma unroll
    for (int r = 0; r < 4; ++r) {
      size_t rowoff = ((size_t)t * BB + b0 + lrow0 + r) * HH + n0 + c16;
      n1v[r] = noise1[rowoff];
      n2v[r] = noise2[rowoff];
    }

    // ================= phase A =================
    f32x4 aA = {0, 0, 0, 0}, aB = {0, 0, 0, 0};
#pragma unroll
    for (int kt = 0; kt < 16; ++kt) {    // W11 x T1 (local, stable)
      short8 a1 = *(const short8*)&T1buf[kt * 512 + lane * 8];
      aA = mfma16(a1, wA[kt], aA);
    }
    stage_poll(pub2, T2buf, (unsigned)t);   // tanh(h2[t])
    __syncthreads();
#pragma unroll
    for (int kt = 0; kt < 16; ++kt) {    // W12 x T2
      short8 a2 = *(const short8*)&T2buf[kt * 512 + lane * 8];
      aB = mfma16(a2, wA[16 + kt], aB);
    }

    // rotated output for step t-1: out[t-1] = tanh(h2[t]) @ wo
    if (t > 0 && slice == ((t - 1) & 7) && w == 0) {
      f32x4 ao = {0, 0, 0, 0};
#pragma unroll
      for (int kt = 0; kt < 16; ++kt) {
        short8 a2 = *(const short8*)&T2buf[kt * 512 + lane * 8];
        short8 bo = *(const short8*)&WOlds[kt * 512 + lane * 8];
        ao = mfma16(a2, bo, ao);
      }
      if (c16 < 3) {
#pragma unroll
        for (int r = 0; r < 4; ++r)
          out[((size_t)(b0 + lrow0 + r) * TT + (t - 1)) * 3 + c16] = ao[r];
      }
    }

    unsigned short tp[4];
#pragma unroll
    for (int r = 0; r < 4; ++r) {
      float pre = aA[r] + aB[r]
                + wis[0] * xstage[buf][lrow0 + r][0]
                + wis[1] * xstage[buf][lrow0 + r][1]
                + wis[2] * xstage[buf][lrow0 + r][2]
                + NOISE_S * n1v[r];
      float h = (1.0f - ALPHA) * h1[r] + ALPHA * pre;
      h1[r] = h;
      tp[r] = f2h(fast_tanh(h));
    }
#pragma unroll
    for (int r = 0; r < 4; ++r)
      __hip_atomic_store(&pub1[pslot + r * 8], tagN | tp[r],
                         __ATOMIC_RELAXED, __HIP_MEMORY_SCOPE_AGENT);

    // ================= phase B =================
    f32x4 bA = {0, 0, 0, 0}, bB = {0, 0, 0, 0};
#pragma unroll
    for (int kt = 0; kt < 16; ++kt) {    // W22 x T2 (register-stable)
      short8 a2 = *(const short8*)&T2buf[kt * 512 + lane * 8];
      bB = mfma16(a2, wB[16 + kt], bB);
    }
    stage_poll(pub1, T1buf, (unsigned)(t + 1));  // fresh tanh(h1')
    if (t + 1 < TT && tid < 80) {
      int b = tid / 5, c = tid % 5;
      xstage[buf ^ 1][b][c] = x[((size_t)(b0 + b) * TT + (t + 1)) * 5 + c];
    }
    __syncthreads();
#pragma unroll
    for (int kt = 0; kt < 16; ++kt) {    // W21 x fresh tanh(h1')
      short8 a1 = *(const short8*)&T1buf[kt * 512 + lane * 8];
      bA = mfma16(a1, wB[kt], bA);
    }
#pragma unroll
    for (int r = 0; r < 4; ++r) {
      float pre = bA[r] + bB[r]
                + wic[0] * xstage[buf][lrow0 + r][3]
                + wic[1] * xstage[buf][lrow0 + r][4]
                + NOISE_S * n2v[r];
      float h = (1.0f - ALPHA) * h2[r] + ALPHA * pre;
      h2[r] = h;
      tp[r] = f2h(fast_tanh(h));
    }
#pragma unroll
    for (int r = 0; r < 4; ++r)
      __hip_atomic_store(&pub2[pslot + r * 8], tagN | tp[r],
                         __ATOMIC_RELAXED, __HIP_MEMORY_SCOPE_AGENT);
  }

  // ---- final output: out[TT-1] = tanh(h2[TT]) @ wo ----
  if (slice == ((TT - 1) & 7)) {
    stage_poll(pub2, T2buf, (unsigned)TT);
    __syncthreads();
    if (w == 0) {
      f32x4 ao = {0, 0, 0, 0};
#pragma unroll
      for (int kt = 0; kt < 16; ++kt) {
        short8 a2 = *(const short8*)&T2buf[kt * 512 + lane * 8];
        short8 bo = *(const short8*)&WOlds[kt * 512 + lane * 8];
        ao = mfma16(a2, bo, ao);
      }
      if (c16 < 3) {
#pragma unroll
        for (int r = 0; r < 4; ++r)
          out[((size_t)(b0 + lrow0 + r) * TT + (TT - 1)) * 3 + c16] = ao[r];
      }
    }
  }
}

extern "C" void kernel_launch(void* const* d_in, const int* in_sizes, int n_in,
                              void* d_out, int out_size, void* d_ws, size_t ws_size,
                              hipStream_t stream) {
  const float* x       = (const float*)d_in[0];
  const float* wi_stim = (const float*)d_in[1];
  const float* w11     = (const float*)d_in[2];
  const float* wi_ctx  = (const float*)d_in[3];
  const float* w22     = (const float*)d_in[4];
  const float* w12     = (const float*)d_in[5];
  const float* w21     = (const float*)d_in[6];
  const float* wo      = (const float*)d_in[7];
  const float* n1      = (const float*)d_in[8];
  const float* n2      = (const float*)d_in[9];
  char* ws = (char*)d_ws;                  // needs ~2.7 MB

  int nz = (NGROUP * 32768 * 2) / 4;       // pub1+pub2 words
  zero_ws<<<64, 256, 0, stream>>>((int*)(ws + PUB1_B), nz);
  pack_weights<<<516, 256, 0, stream>>>(w11, w12, w21, w22, wo,
                                        (unsigned short*)ws);
  rnn_main<<<NSLICE * NGROUP, 256, 0, stream>>>(x, wi_stim, wi_ctx, n1, n2, ws,
                                                (float*)d_out);
}